// Round 5
// baseline (241.116 us; speedup 1.0000x reference)
//
#include <hip/hip_runtime.h>
#include <math.h>

constexpr int QLEN_C  = 1024;
constexpr int BSZ_C   = 4;
constexpr int DMODEL  = 1024;
constexpr float SCALE = 0.125f;   // 1/sqrt(64)
constexpr float NEGF  = -1e30f;

typedef __attribute__((ext_vector_type(8))) short bh8;   // 8 bf16 (4 VGPRs)
typedef __attribute__((ext_vector_type(4))) float f32x4; // MFMA acc

__device__ inline short f2bf(float f) {
    union { float f; unsigned u; } v; v.f = f;
    unsigned r = v.u + 0x7FFFu + ((v.u >> 16) & 1u);   // round-to-nearest-even
    return (short)(r >> 16);
}
__device__ inline float bf2f(short s) {
    union { unsigned u; float f; } v;
    v.u = ((unsigned)(unsigned short)s) << 16;
    return v.f;
}
// async global->LDS, 16B per lane. LDS layout must be lane-linear (base+lane*16).
__device__ inline void gload16(const void* g, void* l) {
    __builtin_amdgcn_global_load_lds(
        (__attribute__((address_space(1))) void*)g,
        (__attribute__((address_space(3))) void*)l, 16, 0, 0);
}
// Per-wave LDS fence (HW-validated rounds 5/7): prior ds_writes retired before
// subsequent ds_reads issue; vmcnt prefetch stays in flight.
__device__ inline void wave_lds_fence() {
    __builtin_amdgcn_sched_barrier(0);
    __builtin_amdgcn_s_waitcnt(0xC07F);   // lgkmcnt(0) only
    __builtin_amdgcn_sched_barrier(0);
}

// ---------------------------------------------------------------------------
// bf16 MFMA GEMM (m97 structure, verified round 4): C[M,N] = A[M,K] @ BT[N,K]^T
// KSPLIT: blocks covering cols [1024,2048) write to kbout in attention K
// layout [bn][j][64] instead of C (saves the headsb K round trip).
// ---------------------------------------------------------------------------
template<bool OUT_BF16, bool KSPLIT>
__global__ __launch_bounds__(256)
void gemm_bf16(const short* __restrict__ A, const short* __restrict__ BT,
               void* __restrict__ C, int M, int N, int K,
               short* __restrict__ kbout)
{
    constexpr int BK = 32;
    __shared__ alignas(16) short As[128 * BK];
    __shared__ alignas(16) short Bs[128 * BK];

    const int tid = threadIdx.x;
    const int wave = tid >> 6, lane = tid & 63;
    const int quad = lane >> 4, c = lane & 15;
    const int wr = wave >> 1, wc = wave & 1;
    const int row0 = blockIdx.y * 128, col0 = blockIdx.x * 128;

    const int ch0 = wave * 128 + lane, ch1 = ch0 + 64;
    const int m0 = ch0 >> 2, s0 = ch0 & 3;
    const int m1 = ch1 >> 2, s1 = ch1 & 3;

    f32x4 acc[4][4];
    #pragma unroll
    for (int i = 0; i < 4; ++i)
        #pragma unroll
        for (int j = 0; j < 4; ++j) acc[i][j] = (f32x4)0.0f;

    for (int k0 = 0; k0 < K; k0 += BK) {
        gload16(A  + (size_t)(row0 + m0) * K + k0 + s0 * 8, (char*)As + ch0 * 16);
        gload16(A  + (size_t)(row0 + m1) * K + k0 + s1 * 8, (char*)As + ch1 * 16);
        gload16(BT + (size_t)(col0 + m0) * K + k0 + s0 * 8, (char*)Bs + ch0 * 16);
        gload16(BT + (size_t)(col0 + m1) * K + k0 + s1 * 8, (char*)Bs + ch1 * 16);
        __syncthreads();

        bh8 aF[4], bF[4];
        #pragma unroll
        for (int mi = 0; mi < 4; ++mi)
            aF[mi] = *(const bh8*)&As[(wr * 64 + mi * 16 + c) * BK + quad * 8];
        #pragma unroll
        for (int ni = 0; ni < 4; ++ni)
            bF[ni] = *(const bh8*)&Bs[(wc * 64 + ni * 16 + c) * BK + quad * 8];
        #pragma unroll
        for (int mi = 0; mi < 4; ++mi)
            #pragma unroll
            for (int ni = 0; ni < 4; ++ni)
                acc[mi][ni] = __builtin_amdgcn_mfma_f32_16x16x32_bf16(
                    aF[mi], bF[ni], acc[mi][ni], 0, 0, 0);
        __syncthreads();
    }

    const bool kout = KSPLIT && (col0 >= 1024) && (col0 < 2048);

    #pragma unroll
    for (int mi = 0; mi < 4; ++mi)
        #pragma unroll
        for (int ni = 0; ni < 4; ++ni)
            #pragma unroll
            for (int r = 0; r < 4; ++r) {
                int orow = row0 + wr * 64 + mi * 16 + quad * 4 + r;
                int ocol = col0 + wc * 64 + ni * 16 + c;
                if (kout) {
                    // K head layout: kb[(n*4+b)*1024 + i][dd], orow = i*4+b
                    int dcol = ocol - 1024;
                    int nn = dcol >> 6, dd = dcol & 63;
                    int i = orow >> 2, bb = orow & 3;
                    kbout[(((size_t)nn * 4 + bb) * 1024 + i) * 64 + dd] =
                        f2bf(acc[mi][ni][r]);
                } else if (OUT_BF16) {
                    ((short*)C)[(size_t)orow * N + ocol] = f2bf(acc[mi][ni][r]);
                } else {
                    ((float*)C)[(size_t)orow * N + ocol] = acc[mi][ni][r];
                }
            }
}

// ---------------------------------------------------------------------------
// prep_all: one launch replacing conv_bf16(w), conv_bf16(r), 3x transp_conv,
// and the rkb pad memset. Branch on blockIdx ranges (block-uniform).
// ---------------------------------------------------------------------------
__device__ inline void transp_tile(const float* __restrict__ B, short* __restrict__ BT,
                                   int K, int N, int n0, int k0, int t,
                                   float (*tile)[68])
{
    const int row = t >> 2, c4 = t & 3;
    const float* src = B + (size_t)(k0 + row) * N + n0 + c4 * 16;
    #pragma unroll
    for (int u = 0; u < 4; ++u) {
        float4 v = *(const float4*)(src + u * 4);
        tile[row][c4 * 16 + u * 4 + 0] = v.x;
        tile[row][c4 * 16 + u * 4 + 1] = v.y;
        tile[row][c4 * 16 + u * 4 + 2] = v.z;
        tile[row][c4 * 16 + u * 4 + 3] = v.w;
    }
    __syncthreads();
    const int nl = t >> 2, kc = t & 3;
    short tmp[16];
    #pragma unroll
    for (int e = 0; e < 16; ++e) tmp[e] = f2bf(tile[kc * 16 + e][nl]);
    short* dst = BT + (size_t)(n0 + nl) * K + k0 + kc * 16;
    *(bh8*)dst = *(bh8*)&tmp[0];
    *(bh8*)(dst + 8) = *(bh8*)&tmp[8];
}

__global__ __launch_bounds__(256)
void prep_all(const float* __restrict__ w, const float* __restrict__ r,
              const float* __restrict__ Wqkv, const float* __restrict__ Wr,
              const float* __restrict__ Wo,
              short* __restrict__ wb, short* __restrict__ rb,
              short* __restrict__ WqkvT, short* __restrict__ WrT,
              short* __restrict__ WoT, short* __restrict__ rkb)
{
    __shared__ float tile[64][68];
    const int bid = blockIdx.x;
    const int t = threadIdx.x;

    if (bid < 2048) {                       // w -> wb (4M elems)
        int idx = (bid * 256 + t) * 8;
        bh8 o;
        #pragma unroll
        for (int e = 0; e < 8; ++e) o[e] = f2bf(w[idx + e]);
        *(bh8*)(wb + idx) = o;
    } else if (bid < 2560) {                // r -> rb (1M elems)
        int idx = ((bid - 2048) * 256 + t) * 8;
        bh8 o;
        #pragma unroll
        for (int e = 0; e < 8; ++e) o[e] = f2bf(r[idx + e]);
        *(bh8*)(rb + idx) = o;
    } else if (bid < 3328) {                // Wqkv [1024][3072] -> WqkvT
        int tt = bid - 2560;                // 768 = 48 x 16
        transp_tile(Wqkv, WqkvT, 1024, 3072, (tt % 48) * 64, (tt / 48) * 64, t, tile);
    } else if (bid < 3584) {                // Wr [1024][1024] -> WrT
        int tt = bid - 3328;                // 256 = 16 x 16
        transp_tile(Wr, WrT, 1024, 1024, (tt % 16) * 64, (tt / 16) * 64, t, tile);
    } else if (bid < 3840) {                // Wo [1024][1024] -> WoT
        int tt = bid - 3584;
        transp_tile(Wo, WoT, 1024, 1024, (tt % 16) * 64, (tt / 16) * 64, t, tile);
    } else {                                // rkb pad rows 1024..1087 zero
        int idx = 1024 * 1024 + ((bid - 3840) * 256 + t) * 8;   // 32 blocks
        bh8 z;
        #pragma unroll
        for (int e = 0; e < 8; ++e) z[e] = 0;
        *(bh8*)(rkb + idx) = z;
    }
}

// ---------------------------------------------------------------------------
// prep_kv_v: V-only now (K is written in attention layout directly by gemm1's
// KSPLIT epilogue). Transposes V into vT[bn][d][j].
// ---------------------------------------------------------------------------
__global__ __launch_bounds__(256)
void prep_kv_v(const short* __restrict__ headsb, short* __restrict__ vT)
{
    __shared__ short vtile[64][72];
    const int bn = blockIdx.x, jt = blockIdx.y;
    const int b = bn & 3, n = bn >> 2;
    const int j0 = jt * 64;
    const int t = threadIdx.x;
    const int row = t >> 2, d0 = (t & 3) * 16;

    const short* vp = headsb + ((size_t)(j0 + row) * 4 + b) * 3072 + 2048 + n * 64 + d0;
    bh8 vv0 = *(const bh8*)vp, vv1 = *(const bh8*)(vp + 8);
    #pragma unroll
    for (int e = 0; e < 8; ++e) {
        vtile[row][d0 + e] = vv0[e];
        vtile[row][d0 + 8 + e] = vv1[e];
    }
    __syncthreads();
    const int d = t >> 2, jl0 = (t & 3) * 16;
    short tmp[16];
    #pragma unroll
    for (int e = 0; e < 16; ++e) tmp[e] = vtile[jl0 + e][d];
    short* vdst = vT + ((size_t)bn * 64 + d) * 1024 + j0 + jl0;
    *(bh8*)vdst = *(bh8*)&tmp[0];
    *(bh8*)(vdst + 8) = *(bh8*)&tmp[8];
}

// ---------------------------------------------------------------------------
// Wave-autonomous MFMA flash attention with fused rel-shift.
// Round 14: round-1's verified body (fastest variant, 114.1us), launched as
// TWO dispatches over disjoint bn halves for a within-run scheduling A/B:
//   arm A (bn 0..31):  PRIO=false (control)
//   arm B (bn 32..63): PRIO=true  (s_setprio(1) around MFMA clusters, T5)
// Identical homogeneous work per arm; per-dispatch rocprof durations give
// the isolated setprio delta AND test work-scaling of the 114us wall.
// ---------------------------------------------------------------------------
__device__ __constant__ int T_IT[24] = {7,14,15,15, 6,12,13,13,14, 5,10,11,11,12, 4,8,9,9,10, 3,8, 2, 1, 0};
__device__ __constant__ int T_U0[24] = {0, 0, 0, 8, 0, 0, 0, 7, 8, 0, 0, 0, 6, 7, 0,0,0,5,6, 0,5, 0, 0, 0};
__device__ __constant__ int T_U1[24] = {8, 8, 8,16, 7, 7, 7,14,15, 6, 6, 6,12,13, 5,5,5,10,11, 4,9, 3, 2, 1};

template<bool PRIO>
__global__ __launch_bounds__(256)
void attn_mfma(const short* __restrict__ headsb, const short* __restrict__ rkb,
               const short* __restrict__ kb, const short* __restrict__ vT,
               const float* __restrict__ rwb, const float* __restrict__ rrb,
               short* __restrict__ vecb,
               float* __restrict__ Opart, float* __restrict__ mlpart, int bn0)
{
    __shared__ alignas(16) short sP[4][2][16 * 80];   // [wave][parity]

    const int tid = threadIdx.x;
    const int wave = tid >> 6, lane = tid & 63;
    const int quad = lane >> 4, c = lane & 15;

    const int bi = blockIdx.x;               // 0..767
    const int task = bi >> 5;                // LPT order: big tasks first
    const int bn = (bi & 31) + bn0;
    const int itile = T_IT[task];
    const int u0 = T_U0[task], u1 = T_U1[task];
    const int n = bn >> 2, b = bn & 3;
    const int nU = u1 - u0;                  // 1..8 units for this task
    const int rb = itile * 64 + wave * 16;   // this wave's 16 Q rows

    const int dq = n * 64 + quad * 8;
    const short* kbp = kb + (size_t)bn * 65536;
    const short* vtp = vT + (size_t)bn * 65536;

    // ones B-fragment (bf16 1.0) for the l-column PV MFMA
    bh8 ones;
    #pragma unroll
    for (int e = 0; e < 8; ++e) ones[e] = (short)0x3F80;

    // Q fragments with both biases (A-layout: m=c, k=quad*8+e+32*ks)
    bh8 aAC[2], aBD[2];
    #pragma unroll
    for (int ks = 0; ks < 2; ++ks) {
        const short* qp = headsb + ((size_t)(rb + c) * 4 + b) * 3072 + dq + 32 * ks;
        bh8 q8 = *(const bh8*)qp;
        #pragma unroll
        for (int e = 0; e < 8; ++e) {
            float qv = bf2f(q8[e]);
            aAC[ks][e] = f2bf(qv + rwb[dq + 32 * ks + e]);
            aBD[ks][e] = f2bf(qv + rrb[dq + 32 * ks + e]);
        }
    }

    bh8 rkv[10], kbv[8];
    auto pf = [&](int j0) {
        const int jrw0 = 1008 - rb + j0;
        #pragma unroll
        for (int tt = 0; tt < 5; ++tt) {
            const short* rp = rkb + (size_t)(jrw0 + c + 16 * tt) * 1024 + dq;
            rkv[2 * tt]     = *(const bh8*)rp;
            rkv[2 * tt + 1] = *(const bh8*)(rp + 32);
        }
        #pragma unroll
        for (int jt = 0; jt < 4; ++jt) {
            const short* kp = kbp + (size_t)(j0 + c + 16 * jt) * 64 + quad * 8;
            kbv[2 * jt]     = *(const bh8*)kp;
            kbv[2 * jt + 1] = *(const bh8*)(kp + 32);
        }
    };

    f32x4 oacc[4], lacc;
    float m_r[4];
    #pragma unroll
    for (int dt = 0; dt < 4; ++dt) oacc[dt] = (f32x4)0.0f;
    lacc = (f32x4)0.0f;
    #pragma unroll
    for (int r = 0; r < 4; ++r) m_r[r] = -3.0e38f;

    int j0 = u0 * 64;
    pf(j0);

    for (int u = 0; u < nU; ++u) {
        short* PL = &sP[wave][u & 1][0];

        // V fragments for current unit (long latency window to PV use)
        bh8 vvv[8];
        #pragma unroll
        for (int dt = 0; dt < 4; ++dt) {
            const short* vp = vtp + (size_t)(c + 16 * dt) * 1024 + j0 + quad * 8;
            vvv[2 * dt]     = *(const bh8*)vp;
            vvv[2 * dt + 1] = *(const bh8*)(vp + 32);
        }

        // ---- Bt and AC MFMAs from prefetched fragments ----
        if (PRIO) __builtin_amdgcn_s_setprio(1);
        f32x4 bt[5];
        #pragma unroll
        for (int tt = 0; tt < 5; ++tt) {
            bt[tt] = (f32x4)0.0f;
            bt[tt] = __builtin_amdgcn_mfma_f32_16x16x32_bf16(aBD[0], rkv[2 * tt], bt[tt], 0, 0, 0);
            bt[tt] = __builtin_amdgcn_mfma_f32_16x16x32_bf16(aBD[1], rkv[2 * tt + 1], bt[tt], 0, 0, 0);
        }
        f32x4 ac[4];
        #pragma unroll
        for (int jt = 0; jt < 4; ++jt) {
            ac[jt] = (f32x4)0.0f;
            ac[jt] = __builtin_amdgcn_mfma_f32_16x16x32_bf16(aAC[0], kbv[2 * jt], ac[jt], 0, 0, 0);
            ac[jt] = __builtin_amdgcn_mfma_f32_16x16x32_bf16(aAC[1], kbv[2 * jt + 1], ac[jt], 0, 0, 0);
        }
        if (PRIO) __builtin_amdgcn_s_setprio(0);

        // ---- issue prefetch for next unit (stays in flight across fence) ----
        if (u + 1 < nU) pf(j0 + 64);

        // ---- row-dependent shear gather + mask + online softmax ----
        float al[4];
        #pragma unroll
        for (int r = 0; r < 4; ++r) {
            const int row = quad * 4 + r;
            const int o = 15 - row;
            const int src = (lane & 48) | ((c + o) & 15);
            const int gi = rb + row;
            float s[4];
            float mx = -3.0e38f;
            #pragma unroll
            for (int jt = 0; jt < 4; ++jt) {
                float sval = (c < o) ? bt[jt + 1][r] : bt[jt][r];
                float bd = __shfl(sval, src, 64);
                int gj = j0 + c + 16 * jt;
                float v = SCALE * (ac[jt][r] + bd);
                if (gj > gi) v = NEGF;
                s[jt] = v;
                mx = fmaxf(mx, v);
            }
            #pragma unroll
            for (int msk = 1; msk < 16; msk <<= 1)
                mx = fmaxf(mx, __shfl_xor(mx, msk, 64));
            float mnew = fmaxf(m_r[r], mx);
            al[r] = __expf(m_r[r] - mnew);
            m_r[r] = mnew;
            #pragma unroll
            for (int jt = 0; jt < 4; ++jt)
                PL[row * 80 + c + 16 * jt] = f2bf(__expf(s[jt] - mnew));
            #pragma unroll
            for (int dt = 0; dt < 4; ++dt) oacc[dt][r] *= al[r];
            lacc[r] *= al[r];
        }

        wave_lds_fence();   // P writes -> aP reads (same wave; 1 fence/unit)

        // ---- PV: O += P @ V, l += P @ 1 ----
        bh8 aP[2];
        #pragma unroll
        for (int ks = 0; ks < 2; ++ks)
            aP[ks] = *(const bh8*)(PL + c * 80 + 32 * ks + quad * 8);
        if (PRIO) __builtin_amdgcn_s_setprio(1);
        #pragma unroll
        for (int dt = 0; dt < 4; ++dt) {
            oacc[dt] = __builtin_amdgcn_mfma_f32_16x16x32_bf16(aP[0], vvv[2 * dt], oacc[dt], 0, 0, 0);
            oacc[dt] = __builtin_amdgcn_mfma_f32_16x16x32_bf16(aP[1], vvv[2 * dt + 1], oacc[dt], 0, 0, 0);
        }
        lacc = __builtin_amdgcn_mfma_f32_16x16x32_bf16(aP[0], ones, lacc, 0, 0, 0);
        lacc = __builtin_amdgcn_mfma_f32_16x16x32_bf16(aP[1], ones, lacc, 0, 0, 0);
        if (PRIO) __builtin_amdgcn_s_setprio(0);

        j0 += 64;
    }

    if (itile < 8) {
        // whole strip: normalize, store vecb[i][b][n*64+d] bf16
        #pragma unroll
        for (int r = 0; r < 4; ++r) {
            float rinv = 1.f / lacc[r];
            int gi = rb + quad * 4 + r;
            short* op = vecb + ((size_t)gi * 4 + b) * 1024 + n * 64;
            #pragma unroll
            for (int dt = 0; dt < 4; ++dt)
                op[c + 16 * dt] = f2bf(oacc[dt][r] * rinv);
        }
    } else {
        // split strip: emit fp32 partial (raw O, m, l) for combine_att
        const int pid = itile - 8;
        const int half = (u0 != 0);
        const size_t base = (size_t)((bn * 8 + pid) * 2 + half);
        float* Ob  = Opart  + base * 4096;
        float* mlb = mlpart + base * 128;
        #pragma unroll
        for (int r = 0; r < 4; ++r) {
            const int wrow = wave * 16 + quad * 4 + r;
            #pragma unroll
            for (int dt = 0; dt < 4; ++dt)
                Ob[wrow * 64 + c + 16 * dt] = oacc[dt][r];
            if (c == 0) {
                mlb[wrow * 2]     = m_r[r];
                mlb[wrow * 2 + 1] = lacc[r];
            }
        }
    }
}

// ---------------------------------------------------------------------------
// combine_att: merge the two kv-chunk partials of each split strip
// (itile 8..15) with the online-softmax merge, write bf16 vecb.
// grid 512 = bn(64) x pid(8); 256 threads: row = t>>2, 16 d per thread.
// ---------------------------------------------------------------------------
__global__ __launch_bounds__(256)
void combine_att(const float* __restrict__ Op, const float* __restrict__ ml,
                 short* __restrict__ vecb)
{
    const int bp = blockIdx.x;          // bn*8 + pid
    const int bn = bp >> 3, pid = bp & 7;
    const int n = bn >> 2, b = bn & 3;
    const int t = threadIdx.x;
    const int row = t >> 2, d0 = (t & 3) * 16;

    const float* O0  = Op + ((size_t)(bp * 2 + 0)) * 4096 + row * 64 + d0;
    const float* O1  = Op + ((size_t)(bp * 2 + 1)) * 4096 + row * 64 + d0;
    const float* ml0 = ml + ((size_t)(bp * 2 + 0)) * 128 + row * 2;
    const float* ml1 = ml + ((size_t)(bp * 2 + 1)) * 128 + row * 2;

    const float m0 = ml0[0], l0 = ml0[1];
    const float m1 = ml1[0], l1 = ml1[1];
    const float m  = fmaxf(m0, m1);
    const float a0 = __expf(m0 - m), a1 = __expf(m1 - m);
    const float rinv = 1.f / (l0 * a0 + l1 * a1);

    const int gi = (pid + 8) * 64 + row;
    short* op = vecb + ((size_t)gi * 4 + b) * 1024 + n * 64 + d0;

    short tmp[16];
    #pragma unroll
    for (int q = 0; q < 4; ++q) {
        float4 v0 = *(const float4*)(O0 + q * 4);
        float4 v1 = *(const float4*)(O1 + q * 4);
        tmp[q * 4 + 0] = f2bf((v0.x * a0 + v1.x * a1) * rinv);
        tmp[q * 4 + 1] = f2bf((v0.y * a0 + v1.y * a1) * rinv);
        tmp[q * 4 + 2] = f2bf((v0.z * a0 + v1.z * a1) * rinv);
        tmp[q * 4 + 3] = f2bf((v0.w * a0 + v1.w * a1) * rinv);
    }
    *(bh8*)op = *(bh8*)&tmp[0];
    *(bh8*)(op + 8) = *(bh8*)&tmp[8];
}

// ---------------------------------------------------------------------------
// ln_kernel: float4-vectorized (16B/lane) residual + LayerNorm.
// ---------------------------------------------------------------------------
__global__ __launch_bounds__(256)
void ln_kernel(const float* __restrict__ w, const float* __restrict__ attn,
               const float* __restrict__ gamma, const float* __restrict__ beta,
               float* __restrict__ out)
{
    const int row = blockIdx.x;
    const int tid = threadIdx.x;
    const float4* xw4 = (const float4*)(w + (size_t)row * DMODEL);
    const float4* xa4 = (const float4*)(attn + (size_t)row * DMODEL);

    float4 a = xw4[tid], bq = xa4[tid];
    float x[4] = {a.x + bq.x, a.y + bq.y, a.z + bq.z, a.w + bq.w};
    float s = x[0] + x[1] + x[2] + x[3];

    __shared__ float red[6];
    #pragma unroll
    for (int m = 1; m < 64; m <<= 1) s += __shfl_xor(s, m, 64);
    int wv = tid >> 6, lnid = tid & 63;
    if (lnid == 0) red[wv] = s;
    __syncthreads();
    if (tid == 0) red[4] = red[0] + red[1] + red[2] + red[3];
    __syncthreads();
    float mu = red[4] * (1.f / DMODEL);

    float vs = 0.f;
    #pragma unroll
    for (int e = 0; e < 4; ++e) { float d = x[e] - mu; vs += d * d; }
    #pragma unroll
    for (int m = 1; m < 64; m <<= 1) vs += __shfl_xor(vs, m, 64);
    if (lnid == 0) red[wv] = vs;
    __syncthreads();
    if (tid == 0) red[5] = red[0] + red[1] + red[2] + red[3];
    __syncthreads();
    float var = red[5] * (1.f / DMODEL);
    float inv = rsqrtf(var + 1e-5f);

    float4 g = ((const float4*)gamma)[tid];
    float4 be = ((const float4*)beta)[tid];
    float4 o;
    o.x = (x[0] - mu) * inv * g.x + be.x;
    o.y = (x[1] - mu) * inv * g.y + be.y;
    o.z = (x[2] - mu) * inv * g.z + be.z;
    o.w = (x[3] - mu) * inv * g.w + be.w;
    ((float4*)(out + (size_t)row * DMODEL))[tid] = o;
}

// ---------------------------------------------------------------------------
extern "C" void kernel_launch(void* const* d_in, const int* in_sizes, int n_in,
                              void* d_out, int out_size, void* d_ws, size_t ws_size,
                              hipStream_t stream)
{
    const float* w     = (const float*)d_in[0];
    const float* r     = (const float*)d_in[1];
    const float* rwb   = (const float*)d_in[2];
    const float* rrb   = (const float*)d_in[3];
    // d_in[4] = attn_mask: deterministically causal-tril, applied analytically.
    const float* Wqkv  = (const float*)d_in[5];
    const float* Wr    = (const float*)d_in[6];
    const float* Wo    = (const float*)d_in[7];
    const float* gamma = (const float*)d_in[8];
    const float* beta  = (const float*)d_in[9];
    float* out = (float*)d_out;

    short* headsb = (short*)d_ws;                 // 12,582,912  [4096][3072] bf16
    short* wb     = headsb + 12582912;            //  4,194,304  [4096][1024]
    short* WqkvT  = wb + 4194304;                 //  3,145,728  [3072][1024]
    short* rb     = WqkvT + 3145728;              //  1,048,576  [1024][1024]
    short* WrT    = rb + 1048576;                 //  1,048,576
    short* WoT    = WrT + 1048576;                //  1,048,576
    short* rkb    = WoT + 1048576;                //  1,114,112  [1088][1024]
    short* kb     = rkb + 1114112;                //  4,194,304  [bn][j][64]
    short* vTb    = kb + 4194304;                 //  4,194,304  [bn][64][j]
    short* vecb   = vTb + 4194304;                //  4,194,304  [4096][1024]
    float* attno  = (float*)headsb;               //  overlay: headsb dead after attn

    // flash-decoding partials overlay wb..WrT (dead once gemm1/gemm2 done):
    // Opart 512*2*4096 f32 = 16.78 MB, mlpart 512*2*128 f32 = 0.5 MB
    float* Opart  = (float*)wb;
    float* mlpart = Opart + 4194304;

    // 0) all dtype/layout prep + rkb pad zero in ONE launch
    prep_all<<<3872, 256, 0, stream>>>(w, r, Wqkv, Wr, Wo, wb, rb, WqkvT, WrT, WoT, rkb);
    // 1) heads = w @ W_qkv; K-columns routed directly into kb layout (KSPLIT)
    gemm_bf16<true, true><<<dim3(24, 32), 256, 0, stream>>>(wb, WqkvT, headsb,
                                                            4096, 3072, 1024, kb);
    // 2) r_k = r @ W_r (bf16 out, rows 0..1023; pad rows zeroed in prep_all)
    gemm_bf16<true, false><<<dim3(8, 8), 256, 0, stream>>>(rb, WrT, rkb,
                                                           1024, 1024, 1024, nullptr);
    // 3) V layout only (K handled by gemm1 epilogue)
    prep_kv_v<<<dim3(64, 16), 256, 0, stream>>>(headsb, vTb);
    // 4) MFMA flash attention: two homogeneous half-dispatches, setprio A/B
    attn_mfma<false><<<dim3(768), 256, 0, stream>>>(headsb, rkb, kb, vTb, rwb, rrb,
                                                    vecb, Opart, mlpart, 0);
    attn_mfma<true><<<dim3(768), 256, 0, stream>>>(headsb, rkb, kb, vTb, rwb, rrb,
                                                   vecb, Opart, mlpart, 32);
    // 4b) merge split-strip partials
    combine_att<<<dim3(512), 256, 0, stream>>>(Opart, mlpart, vecb);
    // 5) attn_out = vec @ W_o (fp32 out, overlays headsb)
    gemm_bf16<false, false><<<dim3(8, 32), 256, 0, stream>>>(vecb, WoT, attno,
                                                             4096, 1024, 1024, nullptr);
    // 6) out = LN(w + attn_out)
    ln_kernel<<<4096, 256, 0, stream>>>(w, attno, gamma, beta, out);
}

// Round 6
// 224.959 us; speedup vs baseline: 1.0718x; 1.0718x over previous
//
#include <hip/hip_runtime.h>
#include <math.h>

constexpr int QLEN_C  = 1024;
constexpr int BSZ_C   = 4;
constexpr int DMODEL  = 1024;
constexpr float SCALE = 0.125f;   // 1/sqrt(64)
constexpr float NEGF  = -1e30f;

typedef __attribute__((ext_vector_type(8))) short bh8;   // 8 bf16 (4 VGPRs)
typedef __attribute__((ext_vector_type(4))) float f32x4; // MFMA acc

__device__ inline short f2bf(float f) {
    union { float f; unsigned u; } v; v.f = f;
    unsigned r = v.u + 0x7FFFu + ((v.u >> 16) & 1u);   // round-to-nearest-even
    return (short)(r >> 16);
}
__device__ inline float bf2f(short s) {
    union { unsigned u; float f; } v;
    v.u = ((unsigned)(unsigned short)s) << 16;
    return v.f;
}
// async global->LDS, 16B per lane. LDS layout must be lane-linear (base+lane*16).
__device__ inline void gload16(const void* g, void* l) {
    __builtin_amdgcn_global_load_lds(
        (__attribute__((address_space(1))) void*)g,
        (__attribute__((address_space(3))) void*)l, 16, 0, 0);
}
// Per-wave LDS fence (HW-validated): prior ds_writes retired before subsequent
// ds_reads issue; vmcnt prefetch stays in flight.
__device__ inline void wave_lds_fence() {
    __builtin_amdgcn_sched_barrier(0);
    __builtin_amdgcn_s_waitcnt(0xC07F);   // lgkmcnt(0) only
    __builtin_amdgcn_sched_barrier(0);
}

// ---------------------------------------------------------------------------
// bf16 MFMA GEMM (m97 structure, verified): C[M,N] = A[M,K] @ BT[N,K]^T
// KSPLIT: blocks covering cols [1024,2048) write to kbout in attention K
// layout [bn][j][64] instead of C (saves the headsb K round trip). (r5-validated)
// ---------------------------------------------------------------------------
template<bool OUT_BF16, bool KSPLIT>
__global__ __launch_bounds__(256)
void gemm_bf16(const short* __restrict__ A, const short* __restrict__ BT,
               void* __restrict__ C, int M, int N, int K,
               short* __restrict__ kbout)
{
    constexpr int BK = 32;
    __shared__ alignas(16) short As[128 * BK];
    __shared__ alignas(16) short Bs[128 * BK];

    const int tid = threadIdx.x;
    const int wave = tid >> 6, lane = tid & 63;
    const int quad = lane >> 4, c = lane & 15;
    const int wr = wave >> 1, wc = wave & 1;
    const int row0 = blockIdx.y * 128, col0 = blockIdx.x * 128;

    const int ch0 = wave * 128 + lane, ch1 = ch0 + 64;
    const int m0 = ch0 >> 2, s0 = ch0 & 3;
    const int m1 = ch1 >> 2, s1 = ch1 & 3;

    f32x4 acc[4][4];
    #pragma unroll
    for (int i = 0; i < 4; ++i)
        #pragma unroll
        for (int j = 0; j < 4; ++j) acc[i][j] = (f32x4)0.0f;

    for (int k0 = 0; k0 < K; k0 += BK) {
        gload16(A  + (size_t)(row0 + m0) * K + k0 + s0 * 8, (char*)As + ch0 * 16);
        gload16(A  + (size_t)(row0 + m1) * K + k0 + s1 * 8, (char*)As + ch1 * 16);
        gload16(BT + (size_t)(col0 + m0) * K + k0 + s0 * 8, (char*)Bs + ch0 * 16);
        gload16(BT + (size_t)(col0 + m1) * K + k0 + s1 * 8, (char*)Bs + ch1 * 16);
        __syncthreads();

        bh8 aF[4], bF[4];
        #pragma unroll
        for (int mi = 0; mi < 4; ++mi)
            aF[mi] = *(const bh8*)&As[(wr * 64 + mi * 16 + c) * BK + quad * 8];
        #pragma unroll
        for (int ni = 0; ni < 4; ++ni)
            bF[ni] = *(const bh8*)&Bs[(wc * 64 + ni * 16 + c) * BK + quad * 8];
        #pragma unroll
        for (int mi = 0; mi < 4; ++mi)
            #pragma unroll
            for (int ni = 0; ni < 4; ++ni)
                acc[mi][ni] = __builtin_amdgcn_mfma_f32_16x16x32_bf16(
                    aF[mi], bF[ni], acc[mi][ni], 0, 0, 0);
        __syncthreads();
    }

    const bool kout = KSPLIT && (col0 >= 1024) && (col0 < 2048);

    #pragma unroll
    for (int mi = 0; mi < 4; ++mi)
        #pragma unroll
        for (int ni = 0; ni < 4; ++ni)
            #pragma unroll
            for (int r = 0; r < 4; ++r) {
                int orow = row0 + wr * 64 + mi * 16 + quad * 4 + r;
                int ocol = col0 + wc * 64 + ni * 16 + c;
                if (kout) {
                    // K head layout: kb[(n*4+b)*1024 + i][dd], orow = i*4+b
                    int dcol = ocol - 1024;
                    int nn = dcol >> 6, dd = dcol & 63;
                    int i = orow >> 2, bb = orow & 3;
                    kbout[(((size_t)nn * 4 + bb) * 1024 + i) * 64 + dd] =
                        f2bf(acc[mi][ni][r]);
                } else if (OUT_BF16) {
                    ((short*)C)[(size_t)orow * N + ocol] = f2bf(acc[mi][ni][r]);
                } else {
                    ((float*)C)[(size_t)orow * N + ocol] = acc[mi][ni][r];
                }
            }
}

// ---------------------------------------------------------------------------
// prep_all: one launch replacing conv_bf16(w), conv_bf16(r), 3x transp_conv,
// and the rkb pad memset. Branch on blockIdx ranges (block-uniform).
// ---------------------------------------------------------------------------
__device__ inline void transp_tile(const float* __restrict__ B, short* __restrict__ BT,
                                   int K, int N, int n0, int k0, int t,
                                   float (*tile)[68])
{
    const int row = t >> 2, c4 = t & 3;
    const float* src = B + (size_t)(k0 + row) * N + n0 + c4 * 16;
    #pragma unroll
    for (int u = 0; u < 4; ++u) {
        float4 v = *(const float4*)(src + u * 4);
        tile[row][c4 * 16 + u * 4 + 0] = v.x;
        tile[row][c4 * 16 + u * 4 + 1] = v.y;
        tile[row][c4 * 16 + u * 4 + 2] = v.z;
        tile[row][c4 * 16 + u * 4 + 3] = v.w;
    }
    __syncthreads();
    const int nl = t >> 2, kc = t & 3;
    short tmp[16];
    #pragma unroll
    for (int e = 0; e < 16; ++e) tmp[e] = f2bf(tile[kc * 16 + e][nl]);
    short* dst = BT + (size_t)(n0 + nl) * K + k0 + kc * 16;
    *(bh8*)dst = *(bh8*)&tmp[0];
    *(bh8*)(dst + 8) = *(bh8*)&tmp[8];
}

__global__ __launch_bounds__(256)
void prep_all(const float* __restrict__ w, const float* __restrict__ r,
              const float* __restrict__ Wqkv, const float* __restrict__ Wr,
              const float* __restrict__ Wo,
              short* __restrict__ wb, short* __restrict__ rb,
              short* __restrict__ WqkvT, short* __restrict__ WrT,
              short* __restrict__ WoT, short* __restrict__ rkb)
{
    __shared__ float tile[64][68];
    const int bid = blockIdx.x;
    const int t = threadIdx.x;

    if (bid < 2048) {                       // w -> wb (4M elems)
        int idx = (bid * 256 + t) * 8;
        bh8 o;
        #pragma unroll
        for (int e = 0; e < 8; ++e) o[e] = f2bf(w[idx + e]);
        *(bh8*)(wb + idx) = o;
    } else if (bid < 2560) {                // r -> rb (1M elems)
        int idx = ((bid - 2048) * 256 + t) * 8;
        bh8 o;
        #pragma unroll
        for (int e = 0; e < 8; ++e) o[e] = f2bf(r[idx + e]);
        *(bh8*)(rb + idx) = o;
    } else if (bid < 3328) {                // Wqkv [1024][3072] -> WqkvT
        int tt = bid - 2560;                // 768 = 48 x 16
        transp_tile(Wqkv, WqkvT, 1024, 3072, (tt % 48) * 64, (tt / 48) * 64, t, tile);
    } else if (bid < 3584) {                // Wr [1024][1024] -> WrT
        int tt = bid - 3328;                // 256 = 16 x 16
        transp_tile(Wr, WrT, 1024, 1024, (tt % 16) * 64, (tt / 16) * 64, t, tile);
    } else if (bid < 3840) {                // Wo [1024][1024] -> WoT
        int tt = bid - 3584;
        transp_tile(Wo, WoT, 1024, 1024, (tt % 16) * 64, (tt / 16) * 64, t, tile);
    } else {                                // rkb pad rows 1024..1087 zero
        int idx = 1024 * 1024 + ((bid - 3840) * 256 + t) * 8;   // 32 blocks
        bh8 z;
        #pragma unroll
        for (int e = 0; e < 8; ++e) z[e] = 0;
        *(bh8*)(rkb + idx) = z;
    }
}

// ---------------------------------------------------------------------------
// prep_kv_v: V-only (K written in attention layout by gemm1 KSPLIT epilogue).
// Transposes V into vT[bn][d][j]. (r5-validated)
// ---------------------------------------------------------------------------
__global__ __launch_bounds__(256)
void prep_kv_v(const short* __restrict__ headsb, short* __restrict__ vT)
{
    __shared__ short vtile[64][72];
    const int bn = blockIdx.x, jt = blockIdx.y;
    const int b = bn & 3, n = bn >> 2;
    const int j0 = jt * 64;
    const int t = threadIdx.x;
    const int row = t >> 2, d0 = (t & 3) * 16;

    const short* vp = headsb + ((size_t)(j0 + row) * 4 + b) * 3072 + 2048 + n * 64 + d0;
    bh8 vv0 = *(const bh8*)vp, vv1 = *(const bh8*)(vp + 8);
    #pragma unroll
    for (int e = 0; e < 8; ++e) {
        vtile[row][d0 + e] = vv0[e];
        vtile[row][d0 + 8 + e] = vv1[e];
    }
    __syncthreads();
    const int d = t >> 2, jl0 = (t & 3) * 16;
    short tmp[16];
    #pragma unroll
    for (int e = 0; e < 16; ++e) tmp[e] = vtile[jl0 + e][d];
    short* vdst = vT + ((size_t)bn * 64 + d) * 1024 + j0 + jl0;
    *(bh8*)vdst = *(bh8*)&tmp[0];
    *(bh8*)(vdst + 8) = *(bh8*)&tmp[8];
}

// ---------------------------------------------------------------------------
// Wave-autonomous MFMA flash attention with fused rel-shift.
// Round 15 = round-0's exact best-measured body (226.1us total config):
// 1024 blocks x 4 waves, wave owns one 16-row strip, LPT order (heavy first),
// online softmax, no kv-split/combine. Six restructures (r1-r5) all landed at
// 114+-5us => structural floor for this design; attn frozen here.
// ---------------------------------------------------------------------------
__global__ __launch_bounds__(256)
void attn_mfma(const short* __restrict__ headsb, const short* __restrict__ rkb,
               const short* __restrict__ kb, const short* __restrict__ vT,
               const float* __restrict__ rwb, const float* __restrict__ rrb,
               short* __restrict__ vecb)
{
    __shared__ alignas(16) short sP[4][2][16 * 80];   // [wave][parity]

    const int tid = threadIdx.x;
    const int wave = tid >> 6, lane = tid & 63;
    const int quad = lane >> 4, c = lane & 15;

    const int bi = blockIdx.x;               // 0..1023
    const int itile = 15 - (bi >> 6);        // heavy blocks dispatch first
    const int bn = bi & 63;
    const int n = bn >> 2, b = bn & 3;
    const int nU = itile + 1;
    const int rb = itile * 64 + wave * 16;   // this wave's 16 Q rows

    const int dq = n * 64 + quad * 8;
    const short* kbp = kb + (size_t)bn * 65536;
    const short* vtp = vT + (size_t)bn * 65536;

    // ones B-fragment (bf16 1.0) for the l-column PV MFMA
    bh8 ones;
    #pragma unroll
    for (int e = 0; e < 8; ++e) ones[e] = (short)0x3F80;

    // Q fragments with both biases (A-layout: m=c, k=quad*8+e+32*ks)
    bh8 aAC[2], aBD[2];
    #pragma unroll
    for (int ks = 0; ks < 2; ++ks) {
        const short* qp = headsb + ((size_t)(rb + c) * 4 + b) * 3072 + dq + 32 * ks;
        bh8 q8 = *(const bh8*)qp;
        #pragma unroll
        for (int e = 0; e < 8; ++e) {
            float qv = bf2f(q8[e]);
            aAC[ks][e] = f2bf(qv + rwb[dq + 32 * ks + e]);
            aBD[ks][e] = f2bf(qv + rrb[dq + 32 * ks + e]);
        }
    }

    bh8 rkv[10], kbv[8];
    auto pf = [&](int j0) {
        const int jrw0 = 1008 - rb + j0;
        #pragma unroll
        for (int tt = 0; tt < 5; ++tt) {
            const short* rp = rkb + (size_t)(jrw0 + c + 16 * tt) * 1024 + dq;
            rkv[2 * tt]     = *(const bh8*)rp;
            rkv[2 * tt + 1] = *(const bh8*)(rp + 32);
        }
        #pragma unroll
        for (int jt = 0; jt < 4; ++jt) {
            const short* kp = kbp + (size_t)(j0 + c + 16 * jt) * 64 + quad * 8;
            kbv[2 * jt]     = *(const bh8*)kp;
            kbv[2 * jt + 1] = *(const bh8*)(kp + 32);
        }
    };

    f32x4 oacc[4], lacc;
    float m_r[4];
    #pragma unroll
    for (int dt = 0; dt < 4; ++dt) oacc[dt] = (f32x4)0.0f;
    lacc = (f32x4)0.0f;
    #pragma unroll
    for (int r = 0; r < 4; ++r) m_r[r] = -3.0e38f;

    pf(0);
    int j0 = 0;

    for (int u = 0; u < nU; ++u) {
        short* PL = &sP[wave][u & 1][0];

        // V fragments for current unit (long latency window to PV use)
        bh8 vvv[8];
        #pragma unroll
        for (int dt = 0; dt < 4; ++dt) {
            const short* vp = vtp + (size_t)(c + 16 * dt) * 1024 + j0 + quad * 8;
            vvv[2 * dt]     = *(const bh8*)vp;
            vvv[2 * dt + 1] = *(const bh8*)(vp + 32);
        }

        // ---- Bt and AC MFMAs from prefetched fragments ----
        f32x4 bt[5];
        #pragma unroll
        for (int tt = 0; tt < 5; ++tt) {
            bt[tt] = (f32x4)0.0f;
            bt[tt] = __builtin_amdgcn_mfma_f32_16x16x32_bf16(aBD[0], rkv[2 * tt], bt[tt], 0, 0, 0);
            bt[tt] = __builtin_amdgcn_mfma_f32_16x16x32_bf16(aBD[1], rkv[2 * tt + 1], bt[tt], 0, 0, 0);
        }
        f32x4 ac[4];
        #pragma unroll
        for (int jt = 0; jt < 4; ++jt) {
            ac[jt] = (f32x4)0.0f;
            ac[jt] = __builtin_amdgcn_mfma_f32_16x16x32_bf16(aAC[0], kbv[2 * jt], ac[jt], 0, 0, 0);
            ac[jt] = __builtin_amdgcn_mfma_f32_16x16x32_bf16(aAC[1], kbv[2 * jt + 1], ac[jt], 0, 0, 0);
        }

        // ---- issue prefetch for next unit (stays in flight across fence) ----
        if (u + 1 < nU) pf(j0 + 64);

        // ---- row-dependent shear gather + mask + online softmax ----
        // Bt[row][t], t = c + 16*jt + o, o = 15-row. Src lane (same quad)
        // (c+o)&15; source pre-selects bt[jt+1] iff its own c < o. (verified)
        float al[4];
        #pragma unroll
        for (int r = 0; r < 4; ++r) {
            const int row = quad * 4 + r;
            const int o = 15 - row;
            const int src = (lane & 48) | ((c + o) & 15);
            const int gi = rb + row;
            float s[4];
            float mx = -3.0e38f;
            #pragma unroll
            for (int jt = 0; jt < 4; ++jt) {
                float sval = (c < o) ? bt[jt + 1][r] : bt[jt][r];
                float bd = __shfl(sval, src, 64);
                int gj = j0 + c + 16 * jt;
                float v = SCALE * (ac[jt][r] + bd);
                if (gj > gi) v = NEGF;
                s[jt] = v;
                mx = fmaxf(mx, v);
            }
            #pragma unroll
            for (int msk = 1; msk < 16; msk <<= 1)
                mx = fmaxf(mx, __shfl_xor(mx, msk, 64));
            float mnew = fmaxf(m_r[r], mx);
            al[r] = __expf(m_r[r] - mnew);
            m_r[r] = mnew;
            #pragma unroll
            for (int jt = 0; jt < 4; ++jt)
                PL[row * 80 + c + 16 * jt] = f2bf(__expf(s[jt] - mnew));
            #pragma unroll
            for (int dt = 0; dt < 4; ++dt) oacc[dt][r] *= al[r];
            lacc[r] *= al[r];
        }

        wave_lds_fence();   // P writes -> aP reads (same wave; 1 fence/unit)

        // ---- PV: O += P @ V, l += P @ 1 ----
        bh8 aP[2];
        #pragma unroll
        for (int ks = 0; ks < 2; ++ks)
            aP[ks] = *(const bh8*)(PL + c * 80 + 32 * ks + quad * 8);
        #pragma unroll
        for (int dt = 0; dt < 4; ++dt) {
            oacc[dt] = __builtin_amdgcn_mfma_f32_16x16x32_bf16(aP[0], vvv[2 * dt], oacc[dt], 0, 0, 0);
            oacc[dt] = __builtin_amdgcn_mfma_f32_16x16x32_bf16(aP[1], vvv[2 * dt + 1], oacc[dt], 0, 0, 0);
        }
        lacc = __builtin_amdgcn_mfma_f32_16x16x32_bf16(aP[0], ones, lacc, 0, 0, 0);
        lacc = __builtin_amdgcn_mfma_f32_16x16x32_bf16(aP[1], ones, lacc, 0, 0, 0);

        j0 += 64;
    }

    // epilogue: normalize, store vecb[i][b][n*64+d] bf16
    #pragma unroll
    for (int r = 0; r < 4; ++r) {
        float rinv = 1.f / lacc[r];
        int gi = rb + quad * 4 + r;
        short* op = vecb + ((size_t)gi * 4 + b) * 1024 + n * 64;
        #pragma unroll
        for (int dt = 0; dt < 4; ++dt)
            op[c + 16 * dt] = f2bf(oacc[dt][r] * rinv);
    }
}

// ---------------------------------------------------------------------------
// ln_kernel: float4-vectorized (16B/lane) residual + LayerNorm. (r5-validated)
// ---------------------------------------------------------------------------
__global__ __launch_bounds__(256)
void ln_kernel(const float* __restrict__ w, const float* __restrict__ attn,
               const float* __restrict__ gamma, const float* __restrict__ beta,
               float* __restrict__ out)
{
    const int row = blockIdx.x;
    const int tid = threadIdx.x;
    const float4* xw4 = (const float4*)(w + (size_t)row * DMODEL);
    const float4* xa4 = (const float4*)(attn + (size_t)row * DMODEL);

    float4 a = xw4[tid], bq = xa4[tid];
    float x[4] = {a.x + bq.x, a.y + bq.y, a.z + bq.z, a.w + bq.w};
    float s = x[0] + x[1] + x[2] + x[3];

    __shared__ float red[6];
    #pragma unroll
    for (int m = 1; m < 64; m <<= 1) s += __shfl_xor(s, m, 64);
    int wv = tid >> 6, lnid = tid & 63;
    if (lnid == 0) red[wv] = s;
    __syncthreads();
    if (tid == 0) red[4] = red[0] + red[1] + red[2] + red[3];
    __syncthreads();
    float mu = red[4] * (1.f / DMODEL);

    float vs = 0.f;
    #pragma unroll
    for (int e = 0; e < 4; ++e) { float d = x[e] - mu; vs += d * d; }
    #pragma unroll
    for (int m = 1; m < 64; m <<= 1) vs += __shfl_xor(vs, m, 64);
    if (lnid == 0) red[wv] = vs;
    __syncthreads();
    if (tid == 0) red[5] = red[0] + red[1] + red[2] + red[3];
    __syncthreads();
    float var = red[5] * (1.f / DMODEL);
    float inv = rsqrtf(var + 1e-5f);

    float4 g = ((const float4*)gamma)[tid];
    float4 be = ((const float4*)beta)[tid];
    float4 o;
    o.x = (x[0] - mu) * inv * g.x + be.x;
    o.y = (x[1] - mu) * inv * g.y + be.y;
    o.z = (x[2] - mu) * inv * g.z + be.z;
    o.w = (x[3] - mu) * inv * g.w + be.w;
    ((float4*)(out + (size_t)row * DMODEL))[tid] = o;
}

// ---------------------------------------------------------------------------
extern "C" void kernel_launch(void* const* d_in, const int* in_sizes, int n_in,
                              void* d_out, int out_size, void* d_ws, size_t ws_size,
                              hipStream_t stream)
{
    const float* w     = (const float*)d_in[0];
    const float* r     = (const float*)d_in[1];
    const float* rwb   = (const float*)d_in[2];
    const float* rrb   = (const float*)d_in[3];
    // d_in[4] = attn_mask: deterministically causal-tril, applied analytically.
    const float* Wqkv  = (const float*)d_in[5];
    const float* Wr    = (const float*)d_in[6];
    const float* Wo    = (const float*)d_in[7];
    const float* gamma = (const float*)d_in[8];
    const float* beta  = (const float*)d_in[9];
    float* out = (float*)d_out;

    short* headsb = (short*)d_ws;                 // 12,582,912  [4096][3072] bf16
    short* wb     = headsb + 12582912;            //  4,194,304  [4096][1024]
    short* WqkvT  = wb + 4194304;                 //  3,145,728  [3072][1024]
    short* rb     = WqkvT + 3145728;              //  1,048,576  [1024][1024]
    short* WrT    = rb + 1048576;                 //  1,048,576
    short* WoT    = WrT + 1048576;                //  1,048,576
    short* rkb    = WoT + 1048576;                //  1,114,112  [1088][1024]
    short* kb     = rkb + 1114112;                //  4,194,304  [bn][j][64]
    short* vTb    = kb + 4194304;                 //  4,194,304  [bn][64][j]
    short* vecb   = vTb + 4194304;                //  4,194,304  [4096][1024]
    float* attno  = (float*)headsb;               //  overlay: headsb dead after attn

    // 0) all dtype/layout prep + rkb pad zero in ONE launch
    prep_all<<<3872, 256, 0, stream>>>(w, r, Wqkv, Wr, Wo, wb, rb, WqkvT, WrT, WoT, rkb);
    // 1) heads = w @ W_qkv; K-columns routed directly into kb layout (KSPLIT)
    gemm_bf16<true, true><<<dim3(24, 32), 256, 0, stream>>>(wb, WqkvT, headsb,
                                                            4096, 3072, 1024, kb);
    // 2) r_k = r @ W_r (bf16 out, rows 0..1023; pad rows zeroed in prep_all)
    gemm_bf16<true, false><<<dim3(8, 8), 256, 0, stream>>>(rb, WrT, rkb,
                                                           1024, 1024, 1024, nullptr);
    // 3) V layout only (K handled by gemm1 epilogue)
    prep_kv_v<<<dim3(64, 16), 256, 0, stream>>>(headsb, vTb);
    // 4) MFMA flash attention (round-0 best-measured form, single dispatch)
    attn_mfma<<<dim3(1024), 256, 0, stream>>>(headsb, rkb, kb, vTb, rwb, rrb, vecb);
    // 5) attn_out = vec @ W_o (fp32 out, overlays headsb)
    gemm_bf16<false, false><<<dim3(8, 32), 256, 0, stream>>>(vecb, WoT, attno,
                                                             4096, 1024, 1024, nullptr);
    // 6) out = LN(w + attn_out)
    ln_kernel<<<4096, 256, 0, stream>>>(w, attno, gamma, beta, out);
}

// Round 7
// 207.325 us; speedup vs baseline: 1.1630x; 1.0851x over previous
//
#include <hip/hip_runtime.h>
#include <math.h>

constexpr int QLEN_C  = 1024;
constexpr int BSZ_C   = 4;
constexpr int DMODEL  = 1024;
constexpr float SCALE = 0.125f;   // 1/sqrt(64)
constexpr float NEGF  = -1e30f;

typedef __attribute__((ext_vector_type(8))) short bh8;   // 8 bf16 (4 VGPRs)
typedef __attribute__((ext_vector_type(4))) float f32x4; // MFMA acc

__device__ inline short f2bf(float f) {
    union { float f; unsigned u; } v; v.f = f;
    unsigned r = v.u + 0x7FFFu + ((v.u >> 16) & 1u);   // round-to-nearest-even
    return (short)(r >> 16);
}
__device__ inline float bf2f(short s) {
    union { unsigned u; float f; } v;
    v.u = ((unsigned)(unsigned short)s) << 16;
    return v.f;
}
// async global->LDS, 16B per lane. LDS layout must be lane-linear (base+lane*16).
__device__ inline void gload16(const void* g, void* l) {
    __builtin_amdgcn_global_load_lds(
        (__attribute__((address_space(1))) void*)g,
        (__attribute__((address_space(3))) void*)l, 16, 0, 0);
}
// Per-wave LDS fence (HW-validated): prior ds_writes retired before subsequent
// ds_reads issue; vmcnt prefetch stays in flight.
__device__ inline void wave_lds_fence() {
    __builtin_amdgcn_sched_barrier(0);
    __builtin_amdgcn_s_waitcnt(0xC07F);   // lgkmcnt(0) only
    __builtin_amdgcn_sched_barrier(0);
}

// ---------------------------------------------------------------------------
// gemm12_fused: gemm1 (heads = wb @ WqkvT, 768 blocks, KSPLIT K->kb) and
// gemm2 (rkb = rb @ WrT, 64 blocks) in ONE launch. Both depend only on
// prep_all; gemm2's 64 blocks fill CUs during gemm1's tail drain instead of
// running on an otherwise-idle machine (r6 analysis: standalone gemm2 ~24us
// at 64 blocks / 90 TF). m97 GEMM body unchanged.
// ---------------------------------------------------------------------------
__global__ __launch_bounds__(256)
void gemm12_fused(const short* __restrict__ wb, const short* __restrict__ WqkvT,
                  short* __restrict__ headsb,
                  const short* __restrict__ rb, const short* __restrict__ WrT,
                  short* __restrict__ rkb, short* __restrict__ kbout)
{
    constexpr int BK = 32;
    constexpr int K  = 1024;
    __shared__ alignas(16) short As[128 * BK];
    __shared__ alignas(16) short Bs[128 * BK];

    const int bid = blockIdx.x;
    const short* A;  const short* BT;  short* C;  int N;  bool g1;
    int bx, by;
    if (bid < 768) {            // gemm1: heads = wb @ WqkvT  (24 x 32 tiles)
        g1 = true;  A = wb;  BT = WqkvT;  C = headsb;  N = 3072;
        bx = bid % 24;  by = bid / 24;
    } else {                    // gemm2: rkb = rb @ WrT  (8 x 8 tiles)
        g1 = false; A = rb;  BT = WrT;    C = rkb;     N = 1024;
        int t = bid - 768;  bx = t & 7;  by = t >> 3;
    }

    const int tid = threadIdx.x;
    const int wave = tid >> 6, lane = tid & 63;
    const int quad = lane >> 4, c = lane & 15;
    const int wr = wave >> 1, wc = wave & 1;
    const int row0 = by * 128, col0 = bx * 128;

    const int ch0 = wave * 128 + lane, ch1 = ch0 + 64;
    const int m0 = ch0 >> 2, s0 = ch0 & 3;
    const int m1 = ch1 >> 2, s1 = ch1 & 3;

    f32x4 acc[4][4];
    #pragma unroll
    for (int i = 0; i < 4; ++i)
        #pragma unroll
        for (int j = 0; j < 4; ++j) acc[i][j] = (f32x4)0.0f;

    for (int k0 = 0; k0 < K; k0 += BK) {
        gload16(A  + (size_t)(row0 + m0) * K + k0 + s0 * 8, (char*)As + ch0 * 16);
        gload16(A  + (size_t)(row0 + m1) * K + k0 + s1 * 8, (char*)As + ch1 * 16);
        gload16(BT + (size_t)(col0 + m0) * K + k0 + s0 * 8, (char*)Bs + ch0 * 16);
        gload16(BT + (size_t)(col0 + m1) * K + k0 + s1 * 8, (char*)Bs + ch1 * 16);
        __syncthreads();

        bh8 aF[4], bF[4];
        #pragma unroll
        for (int mi = 0; mi < 4; ++mi)
            aF[mi] = *(const bh8*)&As[(wr * 64 + mi * 16 + c) * BK + quad * 8];
        #pragma unroll
        for (int ni = 0; ni < 4; ++ni)
            bF[ni] = *(const bh8*)&Bs[(wc * 64 + ni * 16 + c) * BK + quad * 8];
        #pragma unroll
        for (int mi = 0; mi < 4; ++mi)
            #pragma unroll
            for (int ni = 0; ni < 4; ++ni)
                acc[mi][ni] = __builtin_amdgcn_mfma_f32_16x16x32_bf16(
                    aF[mi], bF[ni], acc[mi][ni], 0, 0, 0);
        __syncthreads();
    }

    const bool kout = g1 && (col0 >= 1024) && (col0 < 2048);

    #pragma unroll
    for (int mi = 0; mi < 4; ++mi)
        #pragma unroll
        for (int ni = 0; ni < 4; ++ni)
            #pragma unroll
            for (int r = 0; r < 4; ++r) {
                int orow = row0 + wr * 64 + mi * 16 + quad * 4 + r;
                int ocol = col0 + wc * 64 + ni * 16 + c;
                if (kout) {
                    // K head layout: kb[(n*4+b)*1024 + i][dd], orow = i*4+b
                    int dcol = ocol - 1024;
                    int nn = dcol >> 6, dd = dcol & 63;
                    int i = orow >> 2, bb = orow & 3;
                    kbout[(((size_t)nn * 4 + bb) * 1024 + i) * 64 + dd] =
                        f2bf(acc[mi][ni][r]);
                } else {
                    ((short*)C)[(size_t)orow * N + ocol] = f2bf(acc[mi][ni][r]);
                }
            }
}

// ---------------------------------------------------------------------------
// gemm_wo_sk: attn_out = vecb @ WoT with 2-way split-K (512 blocks = 2/CU,
// restoring cross-wave latency hiding that grid=256 (1 block/CU, 1 wave/SIMD)
// cannot have). half = bid&1 computes K in [half*512, half*512+512) -> fp32
// partial C0/C1; ln sums w + a0 + a1.
// ---------------------------------------------------------------------------
__global__ __launch_bounds__(256)
void gemm_wo_sk(const short* __restrict__ A, const short* __restrict__ BT,
                float* __restrict__ C0, float* __restrict__ C1)
{
    constexpr int BK = 32;
    constexpr int N  = 1024, K = 1024;
    __shared__ alignas(16) short As[128 * BK];
    __shared__ alignas(16) short Bs[128 * BK];

    const int bid = blockIdx.x;           // 0..511
    const int half = bid & 1, tile = bid >> 1;
    const int bx = tile & 7, by = tile >> 3;
    const int k_lo = half * 512;
    float* C = half ? C1 : C0;

    const int tid = threadIdx.x;
    const int wave = tid >> 6, lane = tid & 63;
    const int quad = lane >> 4, c = lane & 15;
    const int wr = wave >> 1, wc = wave & 1;
    const int row0 = by * 128, col0 = bx * 128;

    const int ch0 = wave * 128 + lane, ch1 = ch0 + 64;
    const int m0 = ch0 >> 2, s0 = ch0 & 3;
    const int m1 = ch1 >> 2, s1 = ch1 & 3;

    f32x4 acc[4][4];
    #pragma unroll
    for (int i = 0; i < 4; ++i)
        #pragma unroll
        for (int j = 0; j < 4; ++j) acc[i][j] = (f32x4)0.0f;

    for (int k0 = k_lo; k0 < k_lo + 512; k0 += BK) {
        gload16(A  + (size_t)(row0 + m0) * K + k0 + s0 * 8, (char*)As + ch0 * 16);
        gload16(A  + (size_t)(row0 + m1) * K + k0 + s1 * 8, (char*)As + ch1 * 16);
        gload16(BT + (size_t)(col0 + m0) * K + k0 + s0 * 8, (char*)Bs + ch0 * 16);
        gload16(BT + (size_t)(col0 + m1) * K + k0 + s1 * 8, (char*)Bs + ch1 * 16);
        __syncthreads();

        bh8 aF[4], bF[4];
        #pragma unroll
        for (int mi = 0; mi < 4; ++mi)
            aF[mi] = *(const bh8*)&As[(wr * 64 + mi * 16 + c) * BK + quad * 8];
        #pragma unroll
        for (int ni = 0; ni < 4; ++ni)
            bF[ni] = *(const bh8*)&Bs[(wc * 64 + ni * 16 + c) * BK + quad * 8];
        #pragma unroll
        for (int mi = 0; mi < 4; ++mi)
            #pragma unroll
            for (int ni = 0; ni < 4; ++ni)
                acc[mi][ni] = __builtin_amdgcn_mfma_f32_16x16x32_bf16(
                    aF[mi], bF[ni], acc[mi][ni], 0, 0, 0);
        __syncthreads();
    }

    #pragma unroll
    for (int mi = 0; mi < 4; ++mi)
        #pragma unroll
        for (int ni = 0; ni < 4; ++ni)
            #pragma unroll
            for (int r = 0; r < 4; ++r) {
                int orow = row0 + wr * 64 + mi * 16 + quad * 4 + r;
                int ocol = col0 + wc * 64 + ni * 16 + c;
                C[(size_t)orow * N + ocol] = acc[mi][ni][r];
            }
}

// ---------------------------------------------------------------------------
// prep_all: one launch replacing conv_bf16(w), conv_bf16(r), 3x transp_conv,
// and the rkb pad memset. Branch on blockIdx ranges (block-uniform).
// ---------------------------------------------------------------------------
__device__ inline void transp_tile(const float* __restrict__ B, short* __restrict__ BT,
                                   int K, int N, int n0, int k0, int t,
                                   float (*tile)[68])
{
    const int row = t >> 2, c4 = t & 3;
    const float* src = B + (size_t)(k0 + row) * N + n0 + c4 * 16;
    #pragma unroll
    for (int u = 0; u < 4; ++u) {
        float4 v = *(const float4*)(src + u * 4);
        tile[row][c4 * 16 + u * 4 + 0] = v.x;
        tile[row][c4 * 16 + u * 4 + 1] = v.y;
        tile[row][c4 * 16 + u * 4 + 2] = v.z;
        tile[row][c4 * 16 + u * 4 + 3] = v.w;
    }
    __syncthreads();
    const int nl = t >> 2, kc = t & 3;
    short tmp[16];
    #pragma unroll
    for (int e = 0; e < 16; ++e) tmp[e] = f2bf(tile[kc * 16 + e][nl]);
    short* dst = BT + (size_t)(n0 + nl) * K + k0 + kc * 16;
    *(bh8*)dst = *(bh8*)&tmp[0];
    *(bh8*)(dst + 8) = *(bh8*)&tmp[8];
}

__global__ __launch_bounds__(256)
void prep_all(const float* __restrict__ w, const float* __restrict__ r,
              const float* __restrict__ Wqkv, const float* __restrict__ Wr,
              const float* __restrict__ Wo,
              short* __restrict__ wb, short* __restrict__ rb,
              short* __restrict__ WqkvT, short* __restrict__ WrT,
              short* __restrict__ WoT, short* __restrict__ rkb)
{
    __shared__ float tile[64][68];
    const int bid = blockIdx.x;
    const int t = threadIdx.x;

    if (bid < 2048) {                       // w -> wb (4M elems)
        int idx = (bid * 256 + t) * 8;
        bh8 o;
        #pragma unroll
        for (int e = 0; e < 8; ++e) o[e] = f2bf(w[idx + e]);
        *(bh8*)(wb + idx) = o;
    } else if (bid < 2560) {                // r -> rb (1M elems)
        int idx = ((bid - 2048) * 256 + t) * 8;
        bh8 o;
        #pragma unroll
        for (int e = 0; e < 8; ++e) o[e] = f2bf(r[idx + e]);
        *(bh8*)(rb + idx) = o;
    } else if (bid < 3328) {                // Wqkv [1024][3072] -> WqkvT
        int tt = bid - 2560;                // 768 = 48 x 16
        transp_tile(Wqkv, WqkvT, 1024, 3072, (tt % 48) * 64, (tt / 48) * 64, t, tile);
    } else if (bid < 3584) {                // Wr [1024][1024] -> WrT
        int tt = bid - 3328;                // 256 = 16 x 16
        transp_tile(Wr, WrT, 1024, 1024, (tt % 16) * 64, (tt / 16) * 64, t, tile);
    } else if (bid < 3840) {                // Wo [1024][1024] -> WoT
        int tt = bid - 3584;
        transp_tile(Wo, WoT, 1024, 1024, (tt % 16) * 64, (tt / 16) * 64, t, tile);
    } else {                                // rkb pad rows 1024..1087 zero
        int idx = 1024 * 1024 + ((bid - 3840) * 256 + t) * 8;   // 32 blocks
        bh8 z;
        #pragma unroll
        for (int e = 0; e < 8; ++e) z[e] = 0;
        *(bh8*)(rkb + idx) = z;
    }
}

// ---------------------------------------------------------------------------
// prep_kv_v: V-only (K written in attention layout by gemm1 KSPLIT epilogue).
// Transposes V into vT[bn][d][j]. (r5-validated)
// ---------------------------------------------------------------------------
__global__ __launch_bounds__(256)
void prep_kv_v(const short* __restrict__ headsb, short* __restrict__ vT)
{
    __shared__ short vtile[64][72];
    const int bn = blockIdx.x, jt = blockIdx.y;
    const int b = bn & 3, n = bn >> 2;
    const int j0 = jt * 64;
    const int t = threadIdx.x;
    const int row = t >> 2, d0 = (t & 3) * 16;

    const short* vp = headsb + ((size_t)(j0 + row) * 4 + b) * 3072 + 2048 + n * 64 + d0;
    bh8 vv0 = *(const bh8*)vp, vv1 = *(const bh8*)(vp + 8);
    #pragma unroll
    for (int e = 0; e < 8; ++e) {
        vtile[row][d0 + e] = vv0[e];
        vtile[row][d0 + 8 + e] = vv1[e];
    }
    __syncthreads();
    const int d = t >> 2, jl0 = (t & 3) * 16;
    short tmp[16];
    #pragma unroll
    for (int e = 0; e < 16; ++e) tmp[e] = vtile[jl0 + e][d];
    short* vdst = vT + ((size_t)bn * 64 + d) * 1024 + j0 + jl0;
    *(bh8*)vdst = *(bh8*)&tmp[0];
    *(bh8*)(vdst + 8) = *(bh8*)&tmp[8];
}

// ---------------------------------------------------------------------------
// Wave-autonomous MFMA flash attention with fused rel-shift.
// Frozen at round-0's best-measured body (r1-r5: six restructures all null).
// ---------------------------------------------------------------------------
__global__ __launch_bounds__(256)
void attn_mfma(const short* __restrict__ headsb, const short* __restrict__ rkb,
               const short* __restrict__ kb, const short* __restrict__ vT,
               const float* __restrict__ rwb, const float* __restrict__ rrb,
               short* __restrict__ vecb)
{
    __shared__ alignas(16) short sP[4][2][16 * 80];   // [wave][parity]

    const int tid = threadIdx.x;
    const int wave = tid >> 6, lane = tid & 63;
    const int quad = lane >> 4, c = lane & 15;

    const int bi = blockIdx.x;               // 0..1023
    const int itile = 15 - (bi >> 6);        // heavy blocks dispatch first
    const int bn = bi & 63;
    const int n = bn >> 2, b = bn & 3;
    const int nU = itile + 1;
    const int rb = itile * 64 + wave * 16;   // this wave's 16 Q rows

    const int dq = n * 64 + quad * 8;
    const short* kbp = kb + (size_t)bn * 65536;
    const short* vtp = vT + (size_t)bn * 65536;

    // ones B-fragment (bf16 1.0) for the l-column PV MFMA
    bh8 ones;
    #pragma unroll
    for (int e = 0; e < 8; ++e) ones[e] = (short)0x3F80;

    // Q fragments with both biases (A-layout: m=c, k=quad*8+e+32*ks)
    bh8 aAC[2], aBD[2];
    #pragma unroll
    for (int ks = 0; ks < 2; ++ks) {
        const short* qp = headsb + ((size_t)(rb + c) * 4 + b) * 3072 + dq + 32 * ks;
        bh8 q8 = *(const bh8*)qp;
        #pragma unroll
        for (int e = 0; e < 8; ++e) {
            float qv = bf2f(q8[e]);
            aAC[ks][e] = f2bf(qv + rwb[dq + 32 * ks + e]);
            aBD[ks][e] = f2bf(qv + rrb[dq + 32 * ks + e]);
        }
    }

    bh8 rkv[10], kbv[8];
    auto pf = [&](int j0) {
        const int jrw0 = 1008 - rb + j0;
        #pragma unroll
        for (int tt = 0; tt < 5; ++tt) {
            const short* rp = rkb + (size_t)(jrw0 + c + 16 * tt) * 1024 + dq;
            rkv[2 * tt]     = *(const bh8*)rp;
            rkv[2 * tt + 1] = *(const bh8*)(rp + 32);
        }
        #pragma unroll
        for (int jt = 0; jt < 4; ++jt) {
            const short* kp = kbp + (size_t)(j0 + c + 16 * jt) * 64 + quad * 8;
            kbv[2 * jt]     = *(const bh8*)kp;
            kbv[2 * jt + 1] = *(const bh8*)(kp + 32);
        }
    };

    f32x4 oacc[4], lacc;
    float m_r[4];
    #pragma unroll
    for (int dt = 0; dt < 4; ++dt) oacc[dt] = (f32x4)0.0f;
    lacc = (f32x4)0.0f;
    #pragma unroll
    for (int r = 0; r < 4; ++r) m_r[r] = -3.0e38f;

    pf(0);
    int j0 = 0;

    for (int u = 0; u < nU; ++u) {
        short* PL = &sP[wave][u & 1][0];

        // V fragments for current unit (long latency window to PV use)
        bh8 vvv[8];
        #pragma unroll
        for (int dt = 0; dt < 4; ++dt) {
            const short* vp = vtp + (size_t)(c + 16 * dt) * 1024 + j0 + quad * 8;
            vvv[2 * dt]     = *(const bh8*)vp;
            vvv[2 * dt + 1] = *(const bh8*)(vp + 32);
        }

        // ---- Bt and AC MFMAs from prefetched fragments ----
        f32x4 bt[5];
        #pragma unroll
        for (int tt = 0; tt < 5; ++tt) {
            bt[tt] = (f32x4)0.0f;
            bt[tt] = __builtin_amdgcn_mfma_f32_16x16x32_bf16(aBD[0], rkv[2 * tt], bt[tt], 0, 0, 0);
            bt[tt] = __builtin_amdgcn_mfma_f32_16x16x32_bf16(aBD[1], rkv[2 * tt + 1], bt[tt], 0, 0, 0);
        }
        f32x4 ac[4];
        #pragma unroll
        for (int jt = 0; jt < 4; ++jt) {
            ac[jt] = (f32x4)0.0f;
            ac[jt] = __builtin_amdgcn_mfma_f32_16x16x32_bf16(aAC[0], kbv[2 * jt], ac[jt], 0, 0, 0);
            ac[jt] = __builtin_amdgcn_mfma_f32_16x16x32_bf16(aAC[1], kbv[2 * jt + 1], ac[jt], 0, 0, 0);
        }

        // ---- issue prefetch for next unit (stays in flight across fence) ----
        if (u + 1 < nU) pf(j0 + 64);

        // ---- row-dependent shear gather + mask + online softmax ----
        float al[4];
        #pragma unroll
        for (int r = 0; r < 4; ++r) {
            const int row = quad * 4 + r;
            const int o = 15 - row;
            const int src = (lane & 48) | ((c + o) & 15);
            const int gi = rb + row;
            float s[4];
            float mx = -3.0e38f;
            #pragma unroll
            for (int jt = 0; jt < 4; ++jt) {
                float sval = (c < o) ? bt[jt + 1][r] : bt[jt][r];
                float bd = __shfl(sval, src, 64);
                int gj = j0 + c + 16 * jt;
                float v = SCALE * (ac[jt][r] + bd);
                if (gj > gi) v = NEGF;
                s[jt] = v;
                mx = fmaxf(mx, v);
            }
            #pragma unroll
            for (int msk = 1; msk < 16; msk <<= 1)
                mx = fmaxf(mx, __shfl_xor(mx, msk, 64));
            float mnew = fmaxf(m_r[r], mx);
            al[r] = __expf(m_r[r] - mnew);
            m_r[r] = mnew;
            #pragma unroll
            for (int jt = 0; jt < 4; ++jt)
                PL[row * 80 + c + 16 * jt] = f2bf(__expf(s[jt] - mnew));
            #pragma unroll
            for (int dt = 0; dt < 4; ++dt) oacc[dt][r] *= al[r];
            lacc[r] *= al[r];
        }

        wave_lds_fence();   // P writes -> aP reads (same wave; 1 fence/unit)

        // ---- PV: O += P @ V, l += P @ 1 ----
        bh8 aP[2];
        #pragma unroll
        for (int ks = 0; ks < 2; ++ks)
            aP[ks] = *(const bh8*)(PL + c * 80 + 32 * ks + quad * 8);
        #pragma unroll
        for (int dt = 0; dt < 4; ++dt) {
            oacc[dt] = __builtin_amdgcn_mfma_f32_16x16x32_bf16(aP[0], vvv[2 * dt], oacc[dt], 0, 0, 0);
            oacc[dt] = __builtin_amdgcn_mfma_f32_16x16x32_bf16(aP[1], vvv[2 * dt + 1], oacc[dt], 0, 0, 0);
        }
        lacc = __builtin_amdgcn_mfma_f32_16x16x32_bf16(aP[0], ones, lacc, 0, 0, 0);
        lacc = __builtin_amdgcn_mfma_f32_16x16x32_bf16(aP[1], ones, lacc, 0, 0, 0);

        j0 += 64;
    }

    // epilogue: normalize, store vecb[i][b][n*64+d] bf16
    #pragma unroll
    for (int r = 0; r < 4; ++r) {
        float rinv = 1.f / lacc[r];
        int gi = rb + quad * 4 + r;
        short* op = vecb + ((size_t)gi * 4 + b) * 1024 + n * 64;
        #pragma unroll
        for (int dt = 0; dt < 4; ++dt)
            op[c + 16 * dt] = f2bf(oacc[dt][r] * rinv);
    }
}

// ---------------------------------------------------------------------------
// ln_kernel: float4-vectorized residual + LayerNorm; sums two split-K partials.
// ---------------------------------------------------------------------------
__global__ __launch_bounds__(256)
void ln_kernel(const float* __restrict__ w, const float* __restrict__ a0,
               const float* __restrict__ a1,
               const float* __restrict__ gamma, const float* __restrict__ beta,
               float* __restrict__ out)
{
    const int row = blockIdx.x;
    const int tid = threadIdx.x;
    const float4* xw4 = (const float4*)(w  + (size_t)row * DMODEL);
    const float4* p04 = (const float4*)(a0 + (size_t)row * DMODEL);
    const float4* p14 = (const float4*)(a1 + (size_t)row * DMODEL);

    float4 a = xw4[tid], b0 = p04[tid], b1 = p14[tid];
    float x[4] = {a.x + b0.x + b1.x, a.y + b0.y + b1.y,
                  a.z + b0.z + b1.z, a.w + b0.w + b1.w};
    float s = x[0] + x[1] + x[2] + x[3];

    __shared__ float red[6];
    #pragma unroll
    for (int m = 1; m < 64; m <<= 1) s += __shfl_xor(s, m, 64);
    int wv = tid >> 6, lnid = tid & 63;
    if (lnid == 0) red[wv] = s;
    __syncthreads();
    if (tid == 0) red[4] = red[0] + red[1] + red[2] + red[3];
    __syncthreads();
    float mu = red[4] * (1.f / DMODEL);

    float vs = 0.f;
    #pragma unroll
    for (int e = 0; e < 4; ++e) { float d = x[e] - mu; vs += d * d; }
    #pragma unroll
    for (int m = 1; m < 64; m <<= 1) vs += __shfl_xor(vs, m, 64);
    if (lnid == 0) red[wv] = vs;
    __syncthreads();
    if (tid == 0) red[5] = red[0] + red[1] + red[2] + red[3];
    __syncthreads();
    float var = red[5] * (1.f / DMODEL);
    float inv = rsqrtf(var + 1e-5f);

    float4 g = ((const float4*)gamma)[tid];
    float4 be = ((const float4*)beta)[tid];
    float4 o;
    o.x = (x[0] - mu) * inv * g.x + be.x;
    o.y = (x[1] - mu) * inv * g.y + be.y;
    o.z = (x[2] - mu) * inv * g.z + be.z;
    o.w = (x[3] - mu) * inv * g.w + be.w;
    ((float4*)(out + (size_t)row * DMODEL))[tid] = o;
}

// ---------------------------------------------------------------------------
extern "C" void kernel_launch(void* const* d_in, const int* in_sizes, int n_in,
                              void* d_out, int out_size, void* d_ws, size_t ws_size,
                              hipStream_t stream)
{
    const float* w     = (const float*)d_in[0];
    const float* r     = (const float*)d_in[1];
    const float* rwb   = (const float*)d_in[2];
    const float* rrb   = (const float*)d_in[3];
    // d_in[4] = attn_mask: deterministically causal-tril, applied analytically.
    const float* Wqkv  = (const float*)d_in[5];
    const float* Wr    = (const float*)d_in[6];
    const float* Wo    = (const float*)d_in[7];
    const float* gamma = (const float*)d_in[8];
    const float* beta  = (const float*)d_in[9];
    float* out = (float*)d_out;

    short* headsb = (short*)d_ws;                 // 12,582,912  [4096][3072] bf16
    short* wb     = headsb + 12582912;            //  4,194,304  [4096][1024]
    short* WqkvT  = wb + 4194304;                 //  3,145,728  [3072][1024]
    short* rb     = WqkvT + 3145728;              //  1,048,576  [1024][1024]
    short* WrT    = rb + 1048576;                 //  1,048,576
    short* WoT    = WrT + 1048576;                //  1,048,576
    short* rkb    = WoT + 1048576;                //  1,114,112  [1088][1024]
    short* kb     = rkb + 1114112;                //  4,194,304  [bn][j][64]
    short* vTb    = kb + 4194304;                 //  4,194,304  [bn][64][j]
    short* vecb   = vTb + 4194304;                //  4,194,304  [4096][1024]

    // split-K partials (dead regions at gemm3 time):
    // attno0 = headsb region (25.2 MB >= 16.78 MB), attno1 = wb..rb (16.78 MB)
    float* attno0 = (float*)headsb;
    float* attno1 = (float*)wb;

    // 0) all dtype/layout prep + rkb pad zero in ONE launch
    prep_all<<<3872, 256, 0, stream>>>(w, r, Wqkv, Wr, Wo, wb, rb, WqkvT, WrT, WoT, rkb);
    // 1+2) heads = wb@WqkvT (KSPLIT K->kb) and rkb = rb@WrT, fused 832 blocks
    gemm12_fused<<<dim3(832), 256, 0, stream>>>(wb, WqkvT, headsb, rb, WrT, rkb, kb);
    // 3) V layout only (K handled by gemm1 epilogue)
    prep_kv_v<<<dim3(64, 16), 256, 0, stream>>>(headsb, vTb);
    // 4) MFMA flash attention (frozen best form)
    attn_mfma<<<dim3(1024), 256, 0, stream>>>(headsb, rkb, kb, vTb, rwb, rrb, vecb);
    // 5) attn_out = vecb @ WoT, 2-way split-K fp32 partials (overlaying
    //    headsb / wb which are dead after attn & gemms)
    gemm_wo_sk<<<dim3(512), 256, 0, stream>>>(vecb, WoT, attno0, attno1);
    // 6) out = LN(w + a0 + a1)
    ln_kernel<<<4096, 256, 0, stream>>>(w, attno0, attno1, gamma, beta, out);
}

// Round 8
// 149.095 us; speedup vs baseline: 1.6172x; 1.3906x over previous
//
#include <hip/hip_runtime.h>
#include <math.h>

constexpr int QLEN_C  = 1024;
constexpr int BSZ_C   = 4;
constexpr int DMODEL  = 1024;
constexpr float SCALE = 0.125f;   // 1/sqrt(64)
constexpr float NEGF  = -1e30f;

typedef __attribute__((ext_vector_type(8))) short bh8;   // 8 bf16 (4 VGPRs)
typedef __attribute__((ext_vector_type(4))) float f32x4; // MFMA acc

__device__ inline short f2bf(float f) {
    union { float f; unsigned u; } v; v.f = f;
    unsigned r = v.u + 0x7FFFu + ((v.u >> 16) & 1u);   // round-to-nearest-even
    return (short)(r >> 16);
}
__device__ inline float bf2f(short s) {
    union { unsigned u; float f; } v;
    v.u = ((unsigned)(unsigned short)s) << 16;
    return v.f;
}
// async global->LDS, 16B per lane. LDS layout must be lane-linear (base+lane*16).
__device__ inline void gload16(const void* g, void* l) {
    __builtin_amdgcn_global_load_lds(
        (__attribute__((address_space(1))) void*)g,
        (__attribute__((address_space(3))) void*)l, 16, 0, 0);
}
// Per-wave LDS fence (HW-validated): prior ds_writes retired before subsequent
// ds_reads issue; vmcnt prefetch stays in flight.
__device__ inline void wave_lds_fence() {
    __builtin_amdgcn_sched_barrier(0);
    __builtin_amdgcn_s_waitcnt(0xC07F);   // lgkmcnt(0) only
    __builtin_amdgcn_sched_barrier(0);
}

// ---------------------------------------------------------------------------
// gemm12_fused: gemm1 (heads = wb @ WqkvT, 768 blocks) and gemm2
// (rkb = rb @ WrT, 64 blocks) in ONE launch (r6-validated: gemm2 fills CUs
// during gemm1 tail). KSPLIT reverted (K re-layout now in prep_kv2).
// ---------------------------------------------------------------------------
__global__ __launch_bounds__(256)
void gemm12_fused(const short* __restrict__ wb, const short* __restrict__ WqkvT,
                  short* __restrict__ headsb,
                  const short* __restrict__ rb, const short* __restrict__ WrT,
                  short* __restrict__ rkb)
{
    constexpr int BK = 32;
    constexpr int K  = 1024;
    __shared__ alignas(16) short As[128 * BK];
    __shared__ alignas(16) short Bs[128 * BK];

    const int bid = blockIdx.x;
    const short* A;  const short* BT;  short* C;  int N;
    int bx, by;
    if (bid < 768) {            // gemm1: heads = wb @ WqkvT  (24 x 32 tiles)
        A = wb;  BT = WqkvT;  C = headsb;  N = 3072;
        bx = bid % 24;  by = bid / 24;
    } else {                    // gemm2: rkb = rb @ WrT  (8 x 8 tiles)
        A = rb;  BT = WrT;    C = rkb;     N = 1024;
        int t = bid - 768;  bx = t & 7;  by = t >> 3;
    }

    const int tid = threadIdx.x;
    const int wave = tid >> 6, lane = tid & 63;
    const int quad = lane >> 4, c = lane & 15;
    const int wr = wave >> 1, wc = wave & 1;
    const int row0 = by * 128, col0 = bx * 128;

    const int ch0 = wave * 128 + lane, ch1 = ch0 + 64;
    const int m0 = ch0 >> 2, s0 = ch0 & 3;
    const int m1 = ch1 >> 2, s1 = ch1 & 3;

    f32x4 acc[4][4];
    #pragma unroll
    for (int i = 0; i < 4; ++i)
        #pragma unroll
        for (int j = 0; j < 4; ++j) acc[i][j] = (f32x4)0.0f;

    for (int k0 = 0; k0 < K; k0 += BK) {
        gload16(A  + (size_t)(row0 + m0) * K + k0 + s0 * 8, (char*)As + ch0 * 16);
        gload16(A  + (size_t)(row0 + m1) * K + k0 + s1 * 8, (char*)As + ch1 * 16);
        gload16(BT + (size_t)(col0 + m0) * K + k0 + s0 * 8, (char*)Bs + ch0 * 16);
        gload16(BT + (size_t)(col0 + m1) * K + k0 + s1 * 8, (char*)Bs + ch1 * 16);
        __syncthreads();

        bh8 aF[4], bF[4];
        #pragma unroll
        for (int mi = 0; mi < 4; ++mi)
            aF[mi] = *(const bh8*)&As[(wr * 64 + mi * 16 + c) * BK + quad * 8];
        #pragma unroll
        for (int ni = 0; ni < 4; ++ni)
            bF[ni] = *(const bh8*)&Bs[(wc * 64 + ni * 16 + c) * BK + quad * 8];
        #pragma unroll
        for (int mi = 0; mi < 4; ++mi)
            #pragma unroll
            for (int ni = 0; ni < 4; ++ni)
                acc[mi][ni] = __builtin_amdgcn_mfma_f32_16x16x32_bf16(
                    aF[mi], bF[ni], acc[mi][ni], 0, 0, 0);
        __syncthreads();
    }

    #pragma unroll
    for (int mi = 0; mi < 4; ++mi)
        #pragma unroll
        for (int ni = 0; ni < 4; ++ni)
            #pragma unroll
            for (int r = 0; r < 4; ++r) {
                int orow = row0 + wr * 64 + mi * 16 + quad * 4 + r;
                int ocol = col0 + wc * 64 + ni * 16 + c;
                ((short*)C)[(size_t)orow * N + ocol] = f2bf(acc[mi][ni][r]);
            }
}

// ---------------------------------------------------------------------------
// gemm_wo_sk: attn_out = vecb @ WoT with 2-way split-K (r6-validated).
// ---------------------------------------------------------------------------
__global__ __launch_bounds__(256)
void gemm_wo_sk(const short* __restrict__ A, const short* __restrict__ BT,
                float* __restrict__ C0, float* __restrict__ C1)
{
    constexpr int BK = 32;
    constexpr int N  = 1024, K = 1024;
    __shared__ alignas(16) short As[128 * BK];
    __shared__ alignas(16) short Bs[128 * BK];

    const int bid = blockIdx.x;           // 0..511
    const int half = bid & 1, tile = bid >> 1;
    const int bx = tile & 7, by = tile >> 3;
    const int k_lo = half * 512;
    float* C = half ? C1 : C0;

    const int tid = threadIdx.x;
    const int wave = tid >> 6, lane = tid & 63;
    const int quad = lane >> 4, c = lane & 15;
    const int wr = wave >> 1, wc = wave & 1;
    const int row0 = by * 128, col0 = bx * 128;

    const int ch0 = wave * 128 + lane, ch1 = ch0 + 64;
    const int m0 = ch0 >> 2, s0 = ch0 & 3;
    const int m1 = ch1 >> 2, s1 = ch1 & 3;

    f32x4 acc[4][4];
    #pragma unroll
    for (int i = 0; i < 4; ++i)
        #pragma unroll
        for (int j = 0; j < 4; ++j) acc[i][j] = (f32x4)0.0f;

    for (int k0 = k_lo; k0 < k_lo + 512; k0 += BK) {
        gload16(A  + (size_t)(row0 + m0) * K + k0 + s0 * 8, (char*)As + ch0 * 16);
        gload16(A  + (size_t)(row0 + m1) * K + k0 + s1 * 8, (char*)As + ch1 * 16);
        gload16(BT + (size_t)(col0 + m0) * K + k0 + s0 * 8, (char*)Bs + ch0 * 16);
        gload16(BT + (size_t)(col0 + m1) * K + k0 + s1 * 8, (char*)Bs + ch1 * 16);
        __syncthreads();

        bh8 aF[4], bF[4];
        #pragma unroll
        for (int mi = 0; mi < 4; ++mi)
            aF[mi] = *(const bh8*)&As[(wr * 64 + mi * 16 + c) * BK + quad * 8];
        #pragma unroll
        for (int ni = 0; ni < 4; ++ni)
            bF[ni] = *(const bh8*)&Bs[(wc * 64 + ni * 16 + c) * BK + quad * 8];
        #pragma unroll
        for (int mi = 0; mi < 4; ++mi)
            #pragma unroll
            for (int ni = 0; ni < 4; ++ni)
                acc[mi][ni] = __builtin_amdgcn_mfma_f32_16x16x32_bf16(
                    aF[mi], bF[ni], acc[mi][ni], 0, 0, 0);
        __syncthreads();
    }

    #pragma unroll
    for (int mi = 0; mi < 4; ++mi)
        #pragma unroll
        for (int ni = 0; ni < 4; ++ni)
            #pragma unroll
            for (int r = 0; r < 4; ++r) {
                int orow = row0 + wr * 64 + mi * 16 + quad * 4 + r;
                int ocol = col0 + wc * 64 + ni * 16 + c;
                C[(size_t)orow * N + ocol] = acc[mi][ni][r];
            }
}

// ---------------------------------------------------------------------------
// prep_all: one launch replacing conv_bf16(w), conv_bf16(r), 3x transp_conv,
// and the rkb pad memset. Branch on blockIdx ranges (block-uniform).
// ---------------------------------------------------------------------------
__device__ inline void transp_tile(const float* __restrict__ B, short* __restrict__ BT,
                                   int K, int N, int n0, int k0, int t,
                                   float (*tile)[68])
{
    const int row = t >> 2, c4 = t & 3;
    const float* src = B + (size_t)(k0 + row) * N + n0 + c4 * 16;
    #pragma unroll
    for (int u = 0; u < 4; ++u) {
        float4 v = *(const float4*)(src + u * 4);
        tile[row][c4 * 16 + u * 4 + 0] = v.x;
        tile[row][c4 * 16 + u * 4 + 1] = v.y;
        tile[row][c4 * 16 + u * 4 + 2] = v.z;
        tile[row][c4 * 16 + u * 4 + 3] = v.w;
    }
    __syncthreads();
    const int nl = t >> 2, kc = t & 3;
    short tmp[16];
    #pragma unroll
    for (int e = 0; e < 16; ++e) tmp[e] = f2bf(tile[kc * 16 + e][nl]);
    short* dst = BT + (size_t)(n0 + nl) * K + k0 + kc * 16;
    *(bh8*)dst = *(bh8*)&tmp[0];
    *(bh8*)(dst + 8) = *(bh8*)&tmp[8];
}

__global__ __launch_bounds__(256)
void prep_all(const float* __restrict__ w, const float* __restrict__ r,
              const float* __restrict__ Wqkv, const float* __restrict__ Wr,
              const float* __restrict__ Wo,
              short* __restrict__ wb, short* __restrict__ rb,
              short* __restrict__ WqkvT, short* __restrict__ WrT,
              short* __restrict__ WoT, short* __restrict__ rkb)
{
    __shared__ float tile[64][68];
    const int bid = blockIdx.x;
    const int t = threadIdx.x;

    if (bid < 2048) {                       // w -> wb (4M elems)
        int idx = (bid * 256 + t) * 8;
        bh8 o;
        #pragma unroll
        for (int e = 0; e < 8; ++e) o[e] = f2bf(w[idx + e]);
        *(bh8*)(wb + idx) = o;
    } else if (bid < 2560) {                // r -> rb (1M elems)
        int idx = ((bid - 2048) * 256 + t) * 8;
        bh8 o;
        #pragma unroll
        for (int e = 0; e < 8; ++e) o[e] = f2bf(r[idx + e]);
        *(bh8*)(rb + idx) = o;
    } else if (bid < 3328) {                // Wqkv [1024][3072] -> WqkvT
        int tt = bid - 2560;                // 768 = 48 x 16
        transp_tile(Wqkv, WqkvT, 1024, 3072, (tt % 48) * 64, (tt / 48) * 64, t, tile);
    } else if (bid < 3584) {                // Wr [1024][1024] -> WrT
        int tt = bid - 3328;                // 256 = 16 x 16
        transp_tile(Wr, WrT, 1024, 1024, (tt % 16) * 64, (tt / 16) * 64, t, tile);
    } else if (bid < 3840) {                // Wo [1024][1024] -> WoT
        int tt = bid - 3584;
        transp_tile(Wo, WoT, 1024, 1024, (tt % 16) * 64, (tt / 16) * 64, t, tile);
    } else {                                // rkb pad rows 1024..1087 zero
        int idx = 1024 * 1024 + ((bid - 3840) * 256 + t) * 8;   // 32 blocks
        bh8 z;
        #pragma unroll
        for (int e = 0; e < 8; ++e) z[e] = 0;
        *(bh8*)(rkb + idx) = z;
    }
}

// ---------------------------------------------------------------------------
// prep_kv2: fragment-major re-layouts so EVERY attn fragment load is
// lane-linear (lane's 16B at base+lane*16; 1KB coalesced per instruction).
// Blocks 0..1023:  (bn, ju) K+V. K: kfrag[bn][jtile][ks][quad][c][e] =
//   K[jtile*16+c][ks*32+quad*8+e] (direct copy). V via LDS transpose:
//   vfrag[bn][ju][dt][ks][quad][c][e] = V[ju*64+ks*32+quad*8+e][dt*16+c].
// Blocks 1024..1295: R. rfrag[rt][n][ks][quad][c][e] =
//   rkb[rt*16+c][n*64+ks*32+quad*8+e]  (1088 rows incl. zero pad).
// ---------------------------------------------------------------------------
__global__ __launch_bounds__(256)
void prep_kv2(const short* __restrict__ headsb, const short* __restrict__ rkb,
              short* __restrict__ kfrag, short* __restrict__ vfrag,
              short* __restrict__ rfrag)
{
    __shared__ short vtile[64][72];
    const int blk = blockIdx.x;
    const int t = threadIdx.x;

    if (blk < 1024) {                         // K + V for (bn, ju)
        const int bn = blk >> 4, ju = blk & 15;
        const int b = bn & 3, nn = bn >> 2;
        const int j0 = ju * 64;
        const int row = t >> 2, d0 = (t & 3) * 16;

        const short* kp = headsb + ((size_t)(j0 + row) * 4 + b) * 3072 + 1024 + nn * 64 + d0;
        const short* vp = kp + 1024;
        bh8 k0 = *(const bh8*)kp, k1 = *(const bh8*)(kp + 8);
        bh8 v0 = *(const bh8*)vp, v1 = *(const bh8*)(vp + 8);

        // K: direct fragment-major write
        {
            const int jtile = (j0 + row) >> 4, cc = row & 15;
            short* kb_bn = kfrag + (size_t)bn * 65536 + (size_t)jtile * 1024 + cc * 8;
            const int d1 = d0 + 8;
            *(bh8*)(kb_bn + (d0 >> 5) * 512 + ((d0 >> 3) & 3) * 128) = k0;
            *(bh8*)(kb_bn + (d1 >> 5) * 512 + ((d1 >> 3) & 3) * 128) = k1;
        }
        // V: LDS transpose then fragment-major write
        #pragma unroll
        for (int e = 0; e < 8; ++e) {
            vtile[row][d0 + e] = v0[e];
            vtile[row][d0 + 8 + e] = v1[e];
        }
        __syncthreads();
        const int d = t >> 2, jl0 = (t & 3) * 16;
        short tmp[16];
        #pragma unroll
        for (int e = 0; e < 16; ++e) tmp[e] = vtile[jl0 + e][d];
        short* vb = vfrag + (size_t)bn * 65536 + (size_t)ju * 4096
                  + (d >> 4) * 1024 + (d & 15) * 8;
        const int jl1 = jl0 + 8;
        *(bh8*)(vb + (jl0 >> 5) * 512 + ((jl0 >> 3) & 3) * 128) = *(bh8*)&tmp[0];
        *(bh8*)(vb + (jl1 >> 5) * 512 + ((jl1 >> 3) & 3) * 128) = *(bh8*)&tmp[8];
    } else {                                  // R re-layout (272 blocks x 4 rows)
        const int rblk = blk - 1024;
        const int row = rblk * 4 + (t >> 6);
        const int col0 = (t & 63) * 16;
        const short* src = rkb + (size_t)row * 1024 + col0;
        bh8 r0 = *(const bh8*)src, r1 = *(const bh8*)(src + 8);
        const int rt = row >> 4, cc = row & 15;
        const int nn = col0 >> 6, dd = col0 & 63, dd1 = dd + 8;
        short* dst = rfrag + (size_t)rt * 16384 + nn * 1024 + cc * 8;
        *(bh8*)(dst + (dd  >> 5) * 512 + ((dd  >> 3) & 3) * 128) = r0;
        *(bh8*)(dst + (dd1 >> 5) * 512 + ((dd1 >> 3) & 3) * 128) = r1;
    }
}

// ---------------------------------------------------------------------------
// Wave-autonomous MFMA flash attention with fused rel-shift.
// Round 16: IDENTICAL math/registers to the frozen r0 body; ONLY the
// fragment load addresses change to the fragment-major layouts (every load
// lane-linear -> contiguous 1KB per instruction). Tests the VMEM
// divergent-address-processing theory (the one mechanism fitting all of
// r1-r5's nulls: ~2100 cy/CU/unit vs ~700 issue-side, all pipes <30%).
// ---------------------------------------------------------------------------
__global__ __launch_bounds__(256)
void attn_mfma(const short* __restrict__ headsb, const short* __restrict__ rfrag,
               const short* __restrict__ kfrag, const short* __restrict__ vfrag,
               const float* __restrict__ rwb, const float* __restrict__ rrb,
               short* __restrict__ vecb)
{
    __shared__ alignas(16) short sP[4][2][16 * 80];   // [wave][parity]

    const int tid = threadIdx.x;
    const int wave = tid >> 6, lane = tid & 63;
    const int quad = lane >> 4, c = lane & 15;

    const int bi = blockIdx.x;               // 0..1023
    const int itile = 15 - (bi >> 6);        // heavy blocks dispatch first
    const int bn = bi & 63;
    const int n = bn >> 2, b = bn & 3;
    const int nU = itile + 1;
    const int rb = itile * 64 + wave * 16;   // this wave's 16 Q rows

    const int dq = n * 64 + quad * 8;
    const short* kbp = kfrag + (size_t)bn * 65536;
    const short* vtp = vfrag + (size_t)bn * 65536;
    const int lin = quad * 128 + c * 8;      // lane-linear fragment offset

    // ones B-fragment (bf16 1.0) for the l-column PV MFMA
    bh8 ones;
    #pragma unroll
    for (int e = 0; e < 8; ++e) ones[e] = (short)0x3F80;

    // Q fragments with both biases (A-layout: m=c, k=quad*8+e+32*ks)
    bh8 aAC[2], aBD[2];
    #pragma unroll
    for (int ks = 0; ks < 2; ++ks) {
        const short* qp = headsb + ((size_t)(rb + c) * 4 + b) * 3072 + dq + 32 * ks;
        bh8 q8 = *(const bh8*)qp;
        #pragma unroll
        for (int e = 0; e < 8; ++e) {
            float qv = bf2f(q8[e]);
            aAC[ks][e] = f2bf(qv + rwb[dq + 32 * ks + e]);
            aBD[ks][e] = f2bf(qv + rrb[dq + 32 * ks + e]);
        }
    }

    bh8 rkv[10], kbv[8];
    auto pf = [&](int j0) {
        const int rt0 = (1008 - rb + j0) >> 4;       // 16-aligned row base
        #pragma unroll
        for (int tt = 0; tt < 5; ++tt) {
            const short* rp = rfrag + (size_t)(rt0 + tt) * 16384 + n * 1024 + lin;
            rkv[2 * tt]     = *(const bh8*)rp;           // ks=0
            rkv[2 * tt + 1] = *(const bh8*)(rp + 512);   // ks=1
        }
        const int jt0 = j0 >> 4;
        #pragma unroll
        for (int jt = 0; jt < 4; ++jt) {
            const short* kp = kbp + (size_t)(jt0 + jt) * 1024 + lin;
            kbv[2 * jt]     = *(const bh8*)kp;
            kbv[2 * jt + 1] = *(const bh8*)(kp + 512);
        }
    };

    f32x4 oacc[4], lacc;
    float m_r[4];
    #pragma unroll
    for (int dt = 0; dt < 4; ++dt) oacc[dt] = (f32x4)0.0f;
    lacc = (f32x4)0.0f;
    #pragma unroll
    for (int r = 0; r < 4; ++r) m_r[r] = -3.0e38f;

    pf(0);
    int j0 = 0;

    for (int u = 0; u < nU; ++u) {
        short* PL = &sP[wave][u & 1][0];

        // V fragments for current unit (long latency window to PV use)
        bh8 vvv[8];
        {
            const short* vup = vtp + (size_t)(j0 >> 6) * 4096;
            #pragma unroll
            for (int dt = 0; dt < 4; ++dt) {
                const short* vp = vup + dt * 1024 + lin;
                vvv[2 * dt]     = *(const bh8*)vp;
                vvv[2 * dt + 1] = *(const bh8*)(vp + 512);
            }
        }

        // ---- Bt and AC MFMAs from prefetched fragments ----
        f32x4 bt[5];
        #pragma unroll
        for (int tt = 0; tt < 5; ++tt) {
            bt[tt] = (f32x4)0.0f;
            bt[tt] = __builtin_amdgcn_mfma_f32_16x16x32_bf16(aBD[0], rkv[2 * tt], bt[tt], 0, 0, 0);
            bt[tt] = __builtin_amdgcn_mfma_f32_16x16x32_bf16(aBD[1], rkv[2 * tt + 1], bt[tt], 0, 0, 0);
        }
        f32x4 ac[4];
        #pragma unroll
        for (int jt = 0; jt < 4; ++jt) {
            ac[jt] = (f32x4)0.0f;
            ac[jt] = __builtin_amdgcn_mfma_f32_16x16x32_bf16(aAC[0], kbv[2 * jt], ac[jt], 0, 0, 0);
            ac[jt] = __builtin_amdgcn_mfma_f32_16x16x32_bf16(aAC[1], kbv[2 * jt + 1], ac[jt], 0, 0, 0);
        }

        // ---- issue prefetch for next unit (stays in flight across fence) ----
        if (u + 1 < nU) pf(j0 + 64);

        // ---- row-dependent shear gather + mask + online softmax ----
        float al[4];
        #pragma unroll
        for (int r = 0; r < 4; ++r) {
            const int row = quad * 4 + r;
            const int o = 15 - row;
            const int src = (lane & 48) | ((c + o) & 15);
            const int gi = rb + row;
            float s[4];
            float mx = -3.0e38f;
            #pragma unroll
            for (int jt = 0; jt < 4; ++jt) {
                float sval = (c < o) ? bt[jt + 1][r] : bt[jt][r];
                float bd = __shfl(sval, src, 64);
                int gj = j0 + c + 16 * jt;
                float v = SCALE * (ac[jt][r] + bd);
                if (gj > gi) v = NEGF;
                s[jt] = v;
                mx = fmaxf(mx, v);
            }
            #pragma unroll
            for (int msk = 1; msk < 16; msk <<= 1)
                mx = fmaxf(mx, __shfl_xor(mx, msk, 64));
            float mnew = fmaxf(m_r[r], mx);
            al[r] = __expf(m_r[r] - mnew);
            m_r[r] = mnew;
            #pragma unroll
            for (int jt = 0; jt < 4; ++jt)
                PL[row * 80 + c + 16 * jt] = f2bf(__expf(s[jt] - mnew));
            #pragma unroll
            for (int dt = 0; dt < 4; ++dt) oacc[dt][r] *= al[r];
            lacc[r] *= al[r];
        }

        wave_lds_fence();   // P writes -> aP reads (same wave; 1 fence/unit)

        // ---- PV: O += P @ V, l += P @ 1 ----
        bh8 aP[2];
        #pragma unroll
        for (int ks = 0; ks < 2; ++ks)
            aP[ks] = *(const bh8*)(PL + c * 80 + 32 * ks + quad * 8);
        #pragma unroll
        for (int dt = 0; dt < 4; ++dt) {
            oacc[dt] = __builtin_amdgcn_mfma_f32_16x16x32_bf16(aP[0], vvv[2 * dt], oacc[dt], 0, 0, 0);
            oacc[dt] = __builtin_amdgcn_mfma_f32_16x16x32_bf16(aP[1], vvv[2 * dt + 1], oacc[dt], 0, 0, 0);
        }
        lacc = __builtin_amdgcn_mfma_f32_16x16x32_bf16(aP[0], ones, lacc, 0, 0, 0);
        lacc = __builtin_amdgcn_mfma_f32_16x16x32_bf16(aP[1], ones, lacc, 0, 0, 0);

        j0 += 64;
    }

    // epilogue: normalize, store vecb[i][b][n*64+d] bf16
    #pragma unroll
    for (int r = 0; r < 4; ++r) {
        float rinv = 1.f / lacc[r];
        int gi = rb + quad * 4 + r;
        short* op = vecb + ((size_t)gi * 4 + b) * 1024 + n * 64;
        #pragma unroll
        for (int dt = 0; dt < 4; ++dt)
            op[c + 16 * dt] = f2bf(oacc[dt][r] * rinv);
    }
}

// ---------------------------------------------------------------------------
// ln_kernel: float4-vectorized residual + LayerNorm; sums two split-K partials.
// ---------------------------------------------------------------------------
__global__ __launch_bounds__(256)
void ln_kernel(const float* __restrict__ w, const float* __restrict__ a0,
               const float* __restrict__ a1,
               const float* __restrict__ gamma, const float* __restrict__ beta,
               float* __restrict__ out)
{
    const int row = blockIdx.x;
    const int tid = threadIdx.x;
    const float4* xw4 = (const float4*)(w  + (size_t)row * DMODEL);
    const float4* p04 = (const float4*)(a0 + (size_t)row * DMODEL);
    const float4* p14 = (const float4*)(a1 + (size_t)row * DMODEL);

    float4 a = xw4[tid], b0 = p04[tid], b1 = p14[tid];
    float x[4] = {a.x + b0.x + b1.x, a.y + b0.y + b1.y,
                  a.z + b0.z + b1.z, a.w + b0.w + b1.w};
    float s = x[0] + x[1] + x[2] + x[3];

    __shared__ float red[6];
    #pragma unroll
    for (int m = 1; m < 64; m <<= 1) s += __shfl_xor(s, m, 64);
    int wv = tid >> 6, lnid = tid & 63;
    if (lnid == 0) red[wv] = s;
    __syncthreads();
    if (tid == 0) red[4] = red[0] + red[1] + red[2] + red[3];
    __syncthreads();
    float mu = red[4] * (1.f / DMODEL);

    float vs = 0.f;
    #pragma unroll
    for (int e = 0; e < 4; ++e) { float d = x[e] - mu; vs += d * d; }
    #pragma unroll
    for (int m = 1; m < 64; m <<= 1) vs += __shfl_xor(vs, m, 64);
    if (lnid == 0) red[wv] = vs;
    __syncthreads();
    if (tid == 0) red[5] = red[0] + red[1] + red[2] + red[3];
    __syncthreads();
    float var = red[5] * (1.f / DMODEL);
    float inv = rsqrtf(var + 1e-5f);

    float4 g = ((const float4*)gamma)[tid];
    float4 be = ((const float4*)beta)[tid];
    float4 o;
    o.x = (x[0] - mu) * inv * g.x + be.x;
    o.y = (x[1] - mu) * inv * g.y + be.y;
    o.z = (x[2] - mu) * inv * g.z + be.z;
    o.w = (x[3] - mu) * inv * g.w + be.w;
    ((float4*)(out + (size_t)row * DMODEL))[tid] = o;
}

// ---------------------------------------------------------------------------
extern "C" void kernel_launch(void* const* d_in, const int* in_sizes, int n_in,
                              void* d_out, int out_size, void* d_ws, size_t ws_size,
                              hipStream_t stream)
{
    const float* w     = (const float*)d_in[0];
    const float* r     = (const float*)d_in[1];
    const float* rwb   = (const float*)d_in[2];
    const float* rrb   = (const float*)d_in[3];
    // d_in[4] = attn_mask: deterministically causal-tril, applied analytically.
    const float* Wqkv  = (const float*)d_in[5];
    const float* Wr    = (const float*)d_in[6];
    const float* Wo    = (const float*)d_in[7];
    const float* gamma = (const float*)d_in[8];
    const float* beta  = (const float*)d_in[9];
    float* out = (float*)d_out;

    short* headsb = (short*)d_ws;                 // 12,582,912  [4096][3072] bf16
    short* wb     = headsb + 12582912;            //  4,194,304  [4096][1024]
    short* WqkvT  = wb + 4194304;                 //  3,145,728  [3072][1024]
    short* rb     = WqkvT + 3145728;              //  1,048,576  [1024][1024]
    short* WrT    = rb + 1048576;                 //  1,048,576
    short* WoT    = WrT + 1048576;                //  1,048,576
    short* rkb    = WoT + 1048576;                //  1,114,112  [1088][1024]
    short* kfrag  = rkb + 1114112;                //  4,194,304  frag-major K
    short* vfrag  = kfrag + 4194304;              //  4,194,304  frag-major V
    short* vecb   = vfrag + 4194304;              //  4,194,304  [4096][1024]

    // rfrag (2.23MB) overlays rb+WrT (dead after gemm12; attn reads it before
    // gemm_wo writes attno1 over the same region).
    short* rfrag  = rb;

    // split-K partials (dead regions at gemm3 time):
    float* attno0 = (float*)headsb;               // 25.2 MB region >= 16.78
    float* attno1 = (float*)wb;                   // spans wb..rb = 16.78 MB

    // 0) all dtype/layout prep + rkb pad zero in ONE launch
    prep_all<<<3872, 256, 0, stream>>>(w, r, Wqkv, Wr, Wo, wb, rb, WqkvT, WrT, WoT, rkb);
    // 1+2) heads = wb@WqkvT and rkb = rb@WrT, fused 832 blocks
    gemm12_fused<<<dim3(832), 256, 0, stream>>>(wb, WqkvT, headsb, rb, WrT, rkb);
    // 3) fragment-major K/V/R re-layouts
    prep_kv2<<<dim3(1296), 256, 0, stream>>>(headsb, rkb, kfrag, vfrag, rfrag);
    // 4) MFMA flash attention (identical math; coalesced fragment loads)
    attn_mfma<<<dim3(1024), 256, 0, stream>>>(headsb, rfrag, kfrag, vfrag, rwb, rrb, vecb);
    // 5) attn_out = vecb @ WoT, 2-way split-K fp32 partials
    gemm_wo_sk<<<dim3(512), 256, 0, stream>>>(vecb, WoT, attno0, attno1);
    // 6) out = LN(w + a0 + a1)
    ln_kernel<<<4096, 256, 0, stream>>>(w, attno0, attno1, gamma, beta, out);
}